// Round 8
// baseline (293.409 us; speedup 1.0000x reference)
//
#include <hip/hip_runtime.h>

#define NROWS 8192      // 128 sequences * 64 positions
#define NZX   2304      // z (1024) + xBC (1280) columns from in-proj
#define BCS   136       // Bs/Cs LDS row stride (elements, padded)
#define XMS   72        // XsT/Ms LDS row stride (elements, padded)

// prep kernel block ranges (R10 layout)
#define PB0 4096            // cvt x -> xbf
#define PB1 (PB0 + 2048)    // fold_w
#define PB2 (PB1 + 2304)    // cvt in_w (both dirs)
#define PB3 (PB2 + 256)     // cvtT out_w (both dirs)
#define PB4 (PB3 + 512)     // dt_cs (both dirs, 8 heads/block)

typedef __attribute__((ext_vector_type(8))) short bf16x8;
typedef __attribute__((ext_vector_type(4))) float f32x4;

__device__ __forceinline__ float bf2f(unsigned short u) {
    union { unsigned int i; float f; } v; v.i = ((unsigned int)u) << 16; return v.f;
}
// fast bf16 round (half-up): 2 VALU ops
__device__ __forceinline__ unsigned short f2bf(float f) {
    union { float f; unsigned int i; } v; v.f = f;
    return (unsigned short)((v.i + 0x8000u) >> 16);
}

// async global->LDS, 16B per lane; lane's LDS slot must be wave-base + lane*16.
__device__ __forceinline__ void async_lds16(const unsigned short* g, unsigned short* l) {
    __builtin_amdgcn_global_load_lds(
        (const __attribute__((address_space(1))) unsigned int*)g,
        (__attribute__((address_space(3))) unsigned int*)l, 16, 0, 0);
}

// ---------------------------------------------------------------------------
// PREP: all input conversions + dt/cumsum path, block-range dispatched. (R10)
// ---------------------------------------------------------------------------
__global__ __launch_bounds__(256) void prep_kernel(
    const float* __restrict__ x, const float* __restrict__ fcw,
    const float* __restrict__ iw0, const float* __restrict__ iw1,
    const float* __restrict__ ow0, const float* __restrict__ ow1,
    const float* __restrict__ db0, const float* __restrict__ db1,
    const float* __restrict__ al0, const float* __restrict__ al1,
    unsigned short* __restrict__ xbf, unsigned short* __restrict__ wf,
    unsigned short* __restrict__ wbA, unsigned short* __restrict__ wbOT0,
    unsigned short* __restrict__ wbOT1, float* __restrict__ dtbb,
    float* __restrict__ csbb)
{
    __shared__ char sm[37888] __attribute__((aligned(16)));
    const int blk = blockIdx.x, tid = threadIdx.x;
    if (blk < PB0) {
        int i = blk * 256 + tid;
        float4 v = *(const float4*)(x + (size_t)i * 4);
        ushort4 o;
        o.x = f2bf(v.x); o.y = f2bf(v.y); o.z = f2bf(v.z); o.w = f2bf(v.w);
        *(ushort4*)(xbf + (size_t)i * 4) = o;
    } else if (blk < PB1) {
        int idx = (blk - PB0) * 256 + tid;
        int o = idx >> 10, c = idx & 1023;
        int half = c >> 9, cc = c & 511;
        float v = fcw[(size_t)o * 2048 + half * 1024 + cc] +
                  fcw[(size_t)o * 2048 + half * 1024 + 512 + cc];
        wf[idx] = f2bf(v);
    } else if (blk < PB2) {
        int local = blk - PB1;
        int dir = local / 1152;
        int i = (local % 1152) * 256 + tid;
        const float* s = dir ? iw1 : iw0;
        float4 v = *(const float4*)(s + (size_t)i * 4);
        ushort4 o;
        o.x = f2bf(v.x); o.y = f2bf(v.y); o.z = f2bf(v.z); o.w = f2bf(v.w);
        *(ushort4*)(wbA + (size_t)dir * (2304 * 512) + (size_t)i * 4) = o;
    } else if (blk < PB3) {
        float (*T)[65] = (float(*)[65])sm;
        int local = blk - PB2;
        int z = local >> 7, rem = local & 127;
        const float* s = z ? ow1 : ow0;
        unsigned short* d = z ? wbOT1 : wbOT0;
        const int bo = (rem >> 4) * 64, bc = (rem & 15) * 64;
#pragma unroll
        for (int i = 0; i < 16; ++i) {
            int slot = tid + i * 256;
            int r = slot >> 6, c = slot & 63;
            T[r][c] = s[(size_t)(bo + r) * 1024 + bc + c];
        }
        __syncthreads();
#pragma unroll
        for (int i = 0; i < 16; ++i) {
            int slot = tid + i * 256;
            int cr = slot >> 6, oc = slot & 63;
            d[(size_t)(bc + cr) * 512 + bo + oc] = f2bf(T[oc][cr]);
        }
    } else {
        // dt path fp32, both dirs; 256 blocks per dir; block = (seq, 8-head half)
        float (*wsm)[512] = (float(*)[512])sm;                       // 16 KB
        float (*xs)[68]   = (float(*)[68])(sm + 16384);              // 17.4 KB
        float (*dta)[64]  = (float(*)[64])(sm + 16384 + 17408);      // 2 KB
        float (*dtt)[64]  = (float(*)[64])(sm + 16384 + 17408 + 2048);
        int local = blk - PB3;
        const int dir = local >> 8, bxl = local & 255;
        const float* in_w = dir ? iw1 : iw0;
        const float* dt_bias = dir ? db1 : db0;
        const float* A_log = dir ? al1 : al0;
        float* dtb = dtbb + (size_t)dir * 131072;
        float* csb = csbb + (size_t)dir * 131072;
        const int seq = bxl >> 1, hq = bxl & 1;
#pragma unroll
        for (int i = 0; i < 4; ++i) {
            int slot = tid + i * 256;
            int h = slot >> 7, c = (slot & 127) * 4;
            *(float4*)&wsm[h][c] = *(const float4*)(in_w + (size_t)(2304 + hq * 8 + h) * 512 + c);
        }
        const int t = tid & 63, hg = tid >> 6;   // 2 heads per thread
        float acc[2] = {0.f, 0.f};
        for (int c0 = 0; c0 < 512; c0 += 64) {
            __syncthreads();
#pragma unroll
            for (int i = 0; i < 4; ++i) {
                int slot = tid + i * 256;
                int r = slot >> 4, cc = (slot & 15) * 4;
                size_t row = (dir == 0) ? (size_t)seq * 64 + r
                                        : (size_t)(seq >> 6) * 4096 + (size_t)r * 64 + (seq & 63);
                *(float4*)&xs[r][cc] = *(const float4*)(x + row * 512 + c0 + cc);
            }
            __syncthreads();
#pragma unroll
            for (int cc = 0; cc < 64; cc += 4) {
                float4 u4 = *(const float4*)&xs[t][cc];
                const float* w0 = &wsm[hg * 2][c0 + cc];
                const float* w1 = &wsm[hg * 2 + 1][c0 + cc];
                acc[0] += u4.x * w0[0] + u4.y * w0[1] + u4.z * w0[2] + u4.w * w0[3];
                acc[1] += u4.x * w1[0] + u4.y * w1[1] + u4.z * w1[2] + u4.w * w1[3];
            }
        }
#pragma unroll
        for (int hh = 0; hh < 2; ++hh) {
            int hl = hg * 2 + hh;
            int h = hq * 8 + hl;
            float v = acc[hh] + dt_bias[h];
            float dtv = (v > 20.f) ? v : log1pf(__expf(v));
            dtt[hl][t] = dtv;
            dta[hl][t] = dtv * -__expf(A_log[h]);
        }
        __syncthreads();
        if (tid < 8) {
            float run = 0.f;
            int ob = (seq * 16 + hq * 8 + tid) * 64;
            for (int tt = 0; tt < 64; ++tt) {
                run += dta[tid][tt];
                dtb[ob + tt] = dtt[tid][tt];
                csb[ob + tt] = run;
            }
        }
    }
}

// ---------------------------------------------------------------------------
// gemm_big (R16 = R14 schedule, best measured): 256x256 tiles, 512 threads
// (8 waves, 2M x 4N), BK=64, double-buffered LDS (128 KiB). 2 phases per
// K-tile, fragments read once per K-tile (B held in regs):
//   phase A: wait vmcnt(2); barrier; stage A0',B0'; read B(all)+A0; 32 MFMA
//   phase B: wait vmcnt(4); barrier; stage B1',A1'; read A1;        32 MFMA
// bx<288: in-proj (M=8192,N=2304,K=512; perm on z=1; XCD-swizzled);
// bx>=288: wcomb halves. xBC panels get the register-resident conv+silu
// epilogue -> xbc; z/wcomb panels store bf16 via granule-rotated WR.
// ---------------------------------------------------------------------------
struct GemmEpi { unsigned short* C; int ldc; int colsub; int conv; };

template<int QA, bool LOADB>
__device__ __forceinline__ void mma_half(
    const unsigned short* Ab, const unsigned short* Bb,
    const int (&aoff)[4], const int (&boff)[2], const int (&kcx)[2],
    bf16x8 (&bv)[2][2][2], f32x4 (&acc)[8][4])
{
    bf16x8 av[4][2];
#pragma unroll
    for (int f = 0; f < 4; ++f)
#pragma unroll
        for (int kh = 0; kh < 2; ++kh)
            av[f][kh] = *(const bf16x8*)(Ab + QA * 8192 + aoff[f] + kcx[kh]);
    if (LOADB) {
#pragma unroll
        for (int h = 0; h < 2; ++h)
#pragma unroll
            for (int g = 0; g < 2; ++g)
#pragma unroll
                for (int kh = 0; kh < 2; ++kh)
                    bv[h][g][kh] = *(const bf16x8*)(Bb + h * 8192 + boff[g] + kcx[kh]);
    }
    __builtin_amdgcn_s_setprio(1);
#pragma unroll
    for (int f = 0; f < 4; ++f)
#pragma unroll
        for (int h = 0; h < 2; ++h)
#pragma unroll
            for (int g = 0; g < 2; ++g)
#pragma unroll
                for (int kh = 0; kh < 2; ++kh)
                    acc[QA * 4 + f][h * 2 + g] = __builtin_amdgcn_mfma_f32_16x16x32_bf16(
                        av[f][kh], bv[h][g][kh], acc[QA * 4 + f][h * 2 + g], 0, 0, 0);
    __builtin_amdgcn_s_setprio(0);
}

__global__ __launch_bounds__(512) void gemm_big(
    const unsigned short* __restrict__ xbf, const unsigned short* __restrict__ wbA,
    unsigned short* __restrict__ zx, const unsigned short* __restrict__ wf,
    const unsigned short* __restrict__ wbOT0, const unsigned short* __restrict__ wbOT1,
    unsigned short* __restrict__ wcomb, const float* __restrict__ cw0,
    const float* __restrict__ cw1, const float* __restrict__ cb0,
    const float* __restrict__ cb1, unsigned short* __restrict__ xbc)
{
    __shared__ unsigned short SMEM[65536] __attribute__((aligned(16)));  // 128 KiB
    unsigned short* AS = SMEM;            // [buf][half][128*64]
    unsigned short* BS = SMEM + 32768;
    const int bx = blockIdx.x, z = blockIdx.z;
    const unsigned short *A, *B;
    int lda, perm, mB, nB;
    GemmEpi epi;
    if (bx < 288) {
        // XCD swizzle: 288 tiles/dir; XCD x owns mt in [4x, 4x+4) x all 9 nt.
        int xcd = bx & 7, l = bx >> 3;
        int cid = xcd * 36 + l;
        int mt = cid / 9, nt = cid - mt * 9;
        mB = mt * 256; nB = nt * 256;
        A = xbf; lda = 512; perm = z;
        B = wbA + (size_t)z * (2304 * 512);
        if (nB >= 1024) { epi.C = xbc + (size_t)z * NROWS * 1280; epi.ldc = 1280; epi.colsub = 1024; epi.conv = 1; }
        else            { epi.C = zx + (size_t)z * NROWS * NZX;  epi.ldc = NZX;  epi.colsub = 0;    epi.conv = 0; }
    } else {
        int t2 = bx - 288;
        mB = (t2 >> 2) * 256; nB = (t2 & 3) * 256;
        A = z ? wf : wf + 512; lda = 1024; perm = 0;
        B = z ? wbOT1 : wbOT0;
        epi.C = z ? wcomb : wcomb + 1024; epi.ldc = 2048; epi.colsub = 0; epi.conv = 0;
    }
    const int tid = threadIdx.x, wave = tid >> 6, lane = tid & 63;
    const int wr = wave >> 2, wc = wave & 3;
    const int lr = lane & 15, lq = lane >> 4;
    // ---- staging pointers (2 issues x 2 halves for A and B)
    const unsigned short* gA[2][2];
    const unsigned short* gB[2][2];
    int ldsSlot[2];
#pragma unroll
    for (int i = 0; i < 2; ++i) {
        int s = tid + i * 512;
        int r = s >> 3, p = s & 7, q = p ^ (r & 7);
        ldsSlot[i] = s * 8;
#pragma unroll
        for (int h = 0; h < 2; ++h) {
            int ar = mB + h * 128 + r;
            if (perm) ar = (ar & ~4095) | ((ar & 63) << 6) | ((ar >> 6) & 63);
            gA[i][h] = A + (size_t)ar * lda + q * 8;
            gB[i][h] = B + (size_t)(nB + h * 128 + r) * 512 + q * 8;
        }
    }
    // ---- fragment LDS offsets
    int aoff[4], boff[2], kcx[2];
#pragma unroll
    for (int f = 0; f < 4; ++f) aoff[f] = (wr * 64 + f * 16 + lr) * 64;
#pragma unroll
    for (int g = 0; g < 2; ++g) boff[g] = (wc * 32 + g * 16 + lr) * 64;
#pragma unroll
    for (int kh = 0; kh < 2; ++kh) kcx[kh] = ((kh * 4 + lq) ^ (lr & 7)) * 8;
    f32x4 acc[8][4];
#pragma unroll
    for (int m = 0; m < 8; ++m)
#pragma unroll
        for (int n = 0; n < 4; ++n) acc[m][n] = (f32x4){0.f, 0.f, 0.f, 0.f};

#define STAGE_A(H, K0, CB) { _Pragma("unroll") \
    for (int i = 0; i < 2; ++i) async_lds16(gA[i][H] + (K0), AS + (CB) * 16384 + (H) * 8192 + ldsSlot[i]); }
#define STAGE_B(H, K0, CB) { _Pragma("unroll") \
    for (int i = 0; i < 2; ++i) async_lds16(gB[i][H] + (K0), BS + (CB) * 16384 + (H) * 8192 + ldsSlot[i]); }

    // ---- prologue: tile 0 into buf0, order A0,B0,B1,A1 (A1 last: phase-B-only)
    STAGE_A(0, 0, 0); STAGE_B(0, 0, 0); STAGE_B(1, 0, 0); STAGE_A(1, 0, 0);
    // ---- main loop: tiles 0..6, each stages tile t+1 into the other buffer
#pragma unroll 1
    for (int t = 0; t < 7; ++t) {
        const int cb = t & 1, nb2 = cb ^ 1, k1 = (t + 1) * 64;
        const unsigned short* Ab = AS + cb * 16384;
        const unsigned short* Bb = BS + cb * 16384;
        bf16x8 bv[2][2][2];
        // phase A: needs A0,B0,B1 of t (A1 of t still in flight)
        asm volatile("s_waitcnt vmcnt(2)" ::: "memory");
        asm volatile("s_barrier" ::: "memory");
        STAGE_A(0, k1, nb2); STAGE_B(0, k1, nb2);
        mma_half<0, true>(Ab, Bb, aoff, boff, kcx, bv, acc);
        // phase B: needs A1 of t (t+1's A0,B0 in flight)
        asm volatile("s_waitcnt vmcnt(4)" ::: "memory");
        asm volatile("s_barrier" ::: "memory");
        STAGE_B(1, k1, nb2); STAGE_A(1, k1, nb2);
        mma_half<1, false>(Ab, Bb, aoff, boff, kcx, bv, acc);
    }
    // ---- tail: tile 7 (buf1), no staging
    {
        const unsigned short* Ab = AS + 16384;
        const unsigned short* Bb = BS + 16384;
        bf16x8 bv[2][2][2];
        asm volatile("s_waitcnt vmcnt(2)" ::: "memory");
        asm volatile("s_barrier" ::: "memory");
        mma_half<0, true>(Ab, Bb, aoff, boff, kcx, bv, acc);
        asm volatile("s_waitcnt vmcnt(0)" ::: "memory");
        asm volatile("s_barrier" ::: "memory");
        mma_half<1, false>(Ab, Bb, aoff, boff, kcx, bv, acc);
    }

    // ---- epilogue. WR scratch in buf0 B-region (tile 7 read buf1; disjoint).
    unsigned short* WR = BS + wave * 1024;   // 16 rows x 64 cols per wave
    const int rsl = (lane + 48) & 63;        // lane reads lane-16 (mod 64)
    if (epi.conv) {
        // conv weights/bias for this wave's 64 cols (4 col-frags c4=qb*2+g)
        float4 wv[4]; float bb[4];
#pragma unroll
        for (int c4 = 0; c4 < 4; ++c4) {
            int col = nB - 1024 + (c4 >> 1) * 128 + wc * 32 + (c4 & 1) * 16 + lr;
            const float* cwp = z ? cw1 : cw0;
            const float* cbp = z ? cb1 : cb0;
            wv[c4] = *(const float4*)(cwp + (size_t)col * 4);
            bb[c4] = cbp[col];
        }
#pragma unroll
        for (int h = 0; h < 2; ++h) {
            float pr1[4], pr2[4], pr3[4];
#pragma unroll
            for (int c4 = 0; c4 < 4; ++c4) { pr1[c4] = 0.f; pr2[c4] = 0.f; pr3[c4] = 0.f; }
#pragma unroll
            for (int f = 0; f < 4; ++f) {
#pragma unroll
                for (int c4 = 0; c4 < 4; ++c4) {
                    float vq[4];
#pragma unroll
                    for (int r = 0; r < 4; ++r) vq[r] = acc[h * 4 + f][c4][r];
                    float rc1 = __shfl(vq[1], rsl);
                    float rc2 = __shfl(vq[2], rsl);
                    float rc3 = __shfl(vq[3], rsl);
                    float u1 = lq ? rc3 : pr3[c4];
                    float u2 = lq ? rc2 : pr2[c4];
                    float u3 = lq ? rc1 : pr1[c4];
                    pr1[c4] = rc1; pr2[c4] = rc2; pr3[c4] = rc3;
                    float y4[4];
                    y4[0] = bb[c4] + wv[c4].w*vq[0] + wv[c4].z*u1    + wv[c4].y*u2    + wv[c4].x*u3;
                    y4[1] = bb[c4] + wv[c4].w*vq[1] + wv[c4].z*vq[0] + wv[c4].y*u1    + wv[c4].x*u2;
                    y4[2] = bb[c4] + wv[c4].w*vq[2] + wv[c4].z*vq[1] + wv[c4].y*vq[0] + wv[c4].x*u1;
                    y4[3] = bb[c4] + wv[c4].w*vq[3] + wv[c4].z*vq[2] + wv[c4].y*vq[1] + wv[c4].x*vq[0];
#pragma unroll
                    for (int r = 0; r < 4; ++r) {
                        float a = y4[r];
                        float s = a / (1.f + __expf(-a));
                        int r16 = lq * 4 + r;
                        int cn = c4 * 16 + lr;
                        int gp = ((cn >> 3) + (r16 >> 1)) & 7;
                        WR[r16 * 64 + gp * 8 + (cn & 7)] = f2bf(s);
                    }
                }
#pragma unroll
                for (int j = 0; j < 2; ++j) {
                    int r16 = j * 8 + (lane >> 3);
                    int gr = lane & 7;
                    int gp = (gr + (r16 >> 1)) & 7;
                    uint4 v = *(const uint4*)(WR + r16 * 64 + gp * 8);
                    int row = mB + h * 128 + wr * 64 + f * 16 + r16;
                    int col = nB - epi.colsub + (gr >> 2) * 128 + wc * 32 + ((gr >> 1) & 1) * 16 + (gr & 1) * 8;
                    *(uint4*)(epi.C + (size_t)row * epi.ldc + col) = v;
                }
            }
        }
    } else {
#pragma unroll
        for (int h = 0; h < 2; ++h)
#pragma unroll
            for (int f = 0; f < 4; ++f) {
#pragma unroll
                for (int c4 = 0; c4 < 4; ++c4)
#pragma unroll
                    for (int r = 0; r < 4; ++r) {
                        int r16 = lq * 4 + r;
                        int cn = c4 * 16 + lr;
                        int gp = ((cn >> 3) + (r16 >> 1)) & 7;
                        WR[r16 * 64 + gp * 8 + (cn & 7)] = f2bf(acc[h * 4 + f][c4][r]);
                    }
#pragma unroll
                for (int j = 0; j < 2; ++j) {
                    int r16 = j * 8 + (lane >> 3);
                    int gr = lane & 7;
                    int gp = (gr + (r16 >> 1)) & 7;
                    uint4 v = *(const uint4*)(WR + r16 * 64 + gp * 8);
                    int row = mB + h * 128 + wr * 64 + f * 16 + r16;
                    int col = nB + (gr >> 2) * 128 + wc * 32 + ((gr >> 1) & 1) * 16 + (gr & 1) * 8;
                    *(uint4*)(epi.C + (size_t)row * epi.ldc + col) = v;
                }
            }
    }
#undef STAGE_A
#undef STAGE_B
}

// ---------------------------------------------------------------------------
// Final GEMM, 128x64 tiles, BK=64 (512 blocks), XCD-swizzled. (R11)
// ---------------------------------------------------------------------------
__global__ __launch_bounds__(256) void gemm_final2048(
    const unsigned short* __restrict__ YV, const unsigned short* __restrict__ YH,
    const unsigned short* __restrict__ W, const float* __restrict__ bias,
    float* __restrict__ C)
{
    __shared__ unsigned short As[128 * 64];
    __shared__ unsigned short Bs[64 * 64];
    const int tid = threadIdx.x, wave = tid >> 6, lane = tid & 63;
    const int did = blockIdx.y * 64 + blockIdx.x;   // 0..511
    const int mB = (did >> 3) * 128, nB = (did & 7) * 64;
    const int lr = lane & 15, lq = lane >> 4;
    int aq[4], agr[4], apr[4];
    unsigned short* lA[4];
    const unsigned short* BgP[2];
    unsigned short* lB[2];
#pragma unroll
    for (int i = 0; i < 4; ++i) {
        int s = tid + i * 256;              // A: 1024 slots
        int r = s >> 3, p = s & 7;
        aq[i] = (p ^ (r & 7)) * 8;
        int gr = mB + r;
        agr[i] = gr;
        apr[i] = (gr & ~4095) | ((gr & 63) << 6) | ((gr >> 6) & 63);
        lA[i] = As + s * 8;
    }
#pragma unroll
    for (int i = 0; i < 2; ++i) {
        int s = tid + i * 256;              // B: 512 slots
        int r = s >> 3, p = s & 7;
        int q = p ^ (r & 7);
        BgP[i] = W + (size_t)(nB + r) * 2048 + q * 8;
        lB[i] = Bs + s * 8;
    }
    const int aswz = lr & 7;
    int arb[2], brb[4];
#pragma unroll
    for (int i = 0; i < 2; ++i) arb[i] = (wave * 32 + i * 16 + lr) * 64;
#pragma unroll
    for (int i = 0; i < 4; ++i) brb[i] = (i * 16 + lr) * 64;
    f32x4 zero4 = {0.f,0.f,0.f,0.f};
    f32x4 acc[2][4] = {{zero4,zero4,zero4,zero4},{zero4,zero4,zero4,zero4}};
    for (int k0 = 0; k0 < 2048; k0 += 64) {
#pragma unroll
        for (int i = 0; i < 4; ++i) {
            int kk = k0 + aq[i];
            const unsigned short* g = (kk < 1024)
                ? YV + (size_t)apr[i] * 1024 + kk
                : YH + (size_t)agr[i] * 1024 + (kk - 1024);
            async_lds16(g, lA[i]);
        }
#pragma unroll
        for (int i = 0; i < 2; ++i) async_lds16(BgP[i] + k0, lB[i]);
        __syncthreads();
#pragma unroll
        for (int kh = 0; kh < 2; ++kh) {
            const int ksw = ((kh * 4 + lq) ^ aswz) * 8;
            bf16x8 a[2], b[4];
#pragma unroll
            for (int i = 0; i < 2; ++i) a[i] = *(const bf16x8*)(As + arb[i] + ksw);
#pragma unroll
            for (int i = 0; i < 4; ++i) b[i] = *(const bf16x8*)(Bs + brb[i] + ksw);
#pragma unroll
            for (int mi = 0; mi < 2; ++mi)
#pragma unroll
                for (int ni = 0; ni < 4; ++ni)
                    acc[mi][ni] = __builtin_amdgcn_mfma_f32_16x16x32_bf16(
                        a[mi], b[ni], acc[mi][ni], 0, 0, 0);
        }
        __syncthreads();
    }
    const int rbase = lq * 4;
#pragma unroll
    for (int mi = 0; mi < 2; ++mi)
#pragma unroll
        for (int ni = 0; ni < 4; ++ni) {
            int col = nB + ni * 16 + lr;
            float bb = bias[col];
#pragma unroll
            for (int r = 0; r < 4; ++r) {
                int row = mB + wave * 32 + mi * 16 + rbase + r;
                C[(size_t)row * 512 + col] = acc[mi][ni][r] + bb;
            }
        }
}

// ---------------------------------------------------------------------------
// Scan (R17): gmat FUSED. Per (seq, head) block stages the B/C slices
// (L2-hot, shared by the 16 sibling head-blocks) and computes its own G
// fragments with the EXACT MFMA sequence the old gmat used (same LDS
// layout/stride) -> bit-identical values, no Gbuf round-trip. LDS for
// Bs/Cs (34.8 KB) is reused for XsT/Ms (18.4 KB) after the G compute.
// Triangular skip retained (wave w touches only frags ni <= w; waves 0-1
// skip the kt=1 PV chunk). Numerically identical to R7.
// ---------------------------------------------------------------------------
__global__ __launch_bounds__(256) void scan_kernel(
    const unsigned short* __restrict__ xbcb,
    const float* __restrict__ dtbb, const float* __restrict__ csbb,
    const float* __restrict__ Dv0, const float* __restrict__ Dv1,
    unsigned short* __restrict__ yh, unsigned short* __restrict__ yv)
{
    __shared__ char SM[2 * 64 * BCS * 2] __attribute__((aligned(16)));  // 34816 B
    unsigned short* Bs  = (unsigned short*)SM;                  // 64*BCS
    unsigned short* Cs  = (unsigned short*)(SM + 64 * BCS * 2); // 64*BCS
    unsigned short* XsT = (unsigned short*)SM;                  // reuse after G
    unsigned short* Ms  = (unsigned short*)(SM + 64 * XMS * 2); // reuse after G
    __shared__ float dts[64], css[64];
    const int dir = blockIdx.y;
    const unsigned short* xbc = xbcb + (size_t)dir * NROWS * 1280;
    const float* dtb = dtbb + (size_t)dir * 131072;
    const float* csb = csbb + (size_t)dir * 131072;
    const float* Dv = dir ? Dv1 : Dv0;
    unsigned short* y = dir ? yv : yh;
    const int tid = threadIdx.x;
    const int lane = tid & 63, wave = tid >> 6;
    const int seq = blockIdx.x >> 4, h = blockIdx.x & 15;
    if (tid < 64) {
        dts[tid] = dtb[(seq * 16 + h) * 64 + tid];
        css[tid] = csb[(seq * 16 + h) * 64 + tid];
    }
    const unsigned short* base = xbc + (size_t)seq * 64 * 1280;
    // ---- stage B/C slices (same pattern as old gmat)
#pragma unroll
    for (int i = 0; i < 4; ++i) {
        int e = (tid + i * 256) * 8;
        int r = e >> 7, c = e & 127;
        *(uint4*)(Bs + r * BCS + c) = *(const uint4*)(base + (size_t)r * 1280 + 1024 + c);
        *(uint4*)(Cs + r * BCS + c) = *(const uint4*)(base + (size_t)r * 1280 + 1152 + c);
    }
    __syncthreads();
    const int lr = lane & 15, lq = lane >> 4;
    // ---- compute G fragments (ni <= wave only), identical MFMA sequence
    f32x4 zero4 = {0.f,0.f,0.f,0.f};
    f32x4 acc[4] = {zero4, zero4, zero4, zero4};
#pragma unroll
    for (int kt = 0; kt < 4; ++kt) {
        bf16x8 a = *(const bf16x8*)(Cs + (wave * 16 + lr) * BCS + kt * 32 + lq * 8);
#pragma unroll
        for (int ni = 0; ni < 4; ++ni) {
            if (ni <= wave) {
                bf16x8 b = *(const bf16x8*)(Bs + (ni * 16 + lr) * BCS + kt * 32 + lq * 8);
                acc[ni] = __builtin_amdgcn_mfma_f32_16x16x32_bf16(a, b, acc[ni], 0, 0, 0);
            }
        }
    }
    __syncthreads();   // all Bs/Cs reads complete; region is now reusable
    // ---- load x slice into XsT (overwrites the staging region)
#pragma unroll
    for (int i = 0; i < 2; ++i) {
        int e = (tid + i * 256) * 8;
        int t = e >> 6, p0 = e & 63;
        uint4 xval = *(const uint4*)(base + (size_t)t * 1280 + h * 64 + p0);
        const unsigned short* xs = (const unsigned short*)&xval;
#pragma unroll
        for (int j = 0; j < 8; ++j) {
            int jl = (j + lane) & 7;
            XsT[(p0 + jl) * XMS + t] = xs[jl];
        }
    }
    // ---- build Ms from acc (triangular), zero-fill only what PV reads
    float css_t[4];
#pragma unroll
    for (int r = 0; r < 4; ++r) css_t[r] = css[wave * 16 + lq * 4 + r];
    const int kmax = (wave < 2) ? 2 : 4;   // frags covered by this wave's PV
#pragma unroll
    for (int ni = 0; ni < 4; ++ni) {
        int s = ni * 16 + lr;
        if (ni <= wave) {
            float cs_s = css[s], dt_s = dts[s];
#pragma unroll
            for (int r = 0; r < 4; ++r) {
                int t = wave * 16 + lq * 4 + r;
                float e = __expf(fminf(css_t[r] - cs_s, 0.f));
                float m = (s <= t) ? acc[ni][r] * e * dt_s : 0.f;
                Ms[t * XMS + s] = f2bf(m);
            }
        } else if (ni < kmax) {
#pragma unroll
            for (int r = 0; r < 4; ++r) {
                int t = wave * 16 + lq * 4 + r;
                Ms[t * XMS + s] = 0;
            }
        }
    }
    __syncthreads();
    f32x4 yacc[4] = {zero4, zero4, zero4, zero4};
    const int ktn = (wave < 2) ? 1 : 2;
#pragma unroll
    for (int kt = 0; kt < 2; ++kt) {
        if (kt < ktn) {
            bf16x8 a = *(const bf16x8*)(Ms + (wave * 16 + lr) * XMS + kt * 32 + lq * 8);
#pragma unroll
            for (int ni = 0; ni < 4; ++ni) {
                bf16x8 b = *(const bf16x8*)(XsT + (ni * 16 + lr) * XMS + kt * 32 + lq * 8);
                yacc[ni] = __builtin_amdgcn_mfma_f32_16x16x32_bf16(a, b, yacc[ni], 0, 0, 0);
            }
        }
    }
    const float Dh = Dv[h];
    // stage y[t][p] into Ms rows (own wave band), then coalesced stores
#pragma unroll
    for (int ni = 0; ni < 4; ++ni) {
        int p = ni * 16 + lr;
#pragma unroll
        for (int r = 0; r < 4; ++r) {
            int t = wave * 16 + lq * 4 + r;
            float v = yacc[ni][r] + Dh * bf2f(XsT[p * XMS + t]);
            Ms[t * XMS + p] = f2bf(v);
        }
    }
    __syncthreads();
    unsigned short* yout = y + (size_t)seq * 64 * 1024 + h * 64;
#pragma unroll
    for (int i = 0; i < 2; ++i) {
        int slot = tid + i * 256;      // 512 slots = 64 rows x 8 chunks
        int t = slot >> 3, pc = (slot & 7) * 8;
        uint4 v = *(const uint4*)(Ms + t * XMS + pc);
        *(uint4*)(yout + (size_t)t * 1024 + pc) = v;
    }
}

// ---------------------------------------------------------------------------
// Gate with silu(z) + RMSNorm, dir-merged: grid (8192, 2). (R10)
// ---------------------------------------------------------------------------
__global__ __launch_bounds__(128) void gate_norm(
    const unsigned short* __restrict__ zxb, unsigned short* __restrict__ yh,
    unsigned short* __restrict__ yv, const float* __restrict__ nw0,
    const float* __restrict__ nw1)
{
    const int dir = blockIdx.y;
    const unsigned short* zx = zxb + (size_t)dir * NROWS * NZX;
    unsigned short* y = dir ? yv : yh;
    const float* nw = dir ? nw1 : nw0;
    const int row = blockIdx.x, tid = threadIdx.x;
    uint4 yv4 = *(const uint4*)(y + (size_t)row * 1024 + tid * 8);
    uint4 zv4 = *(const uint4*)(zx + (size_t)row * NZX + tid * 8);
    const unsigned short* ys = (const unsigned short*)&yv4;
    const unsigned short* zs = (const unsigned short*)&zv4;
    float g[8]; float ss = 0.f;
#pragma unroll
    for (int j = 0; j < 8; ++j) {
        float zv = bf2f(zs[j]);
        float gv = bf2f(ys[j]) * (zv / (1.f + __expf(-zv)));
        g[j] = gv; ss += gv * gv;
    }
#pragma unroll
    for (int off = 32; off > 0; off >>= 1) ss += __shfl_xor(ss, off, 64);
    __shared__ float red[2];
    if ((tid & 63) == 0) red[tid >> 6] = ss;
    __syncthreads();
    ss = red[0] + red[1];
    const float scale = rsqrtf(ss * (1.f / 1024.f) + 1e-5f);
    unsigned short out8[8] __attribute__((aligned(16)));
#pragma unroll
    for (int j = 0; j < 8; ++j) out8[j] = f2bf(g[j] * scale * nw[tid * 8 + j]);
    *(uint4*)(y + (size_t)row * 1024 + tid * 8) = *(const uint4*)out8;
}

extern "C" void kernel_launch(void* const* d_in, const int* in_sizes, int n_in,
                              void* d_out, int out_size, void* d_ws, size_t ws_size,
                              hipStream_t stream)
{
    (void)in_sizes; (void)n_in; (void)out_size; (void)ws_size;
    const float* x   = (const float*)d_in[0];
    const float* fcw = (const float*)d_in[17];
    const float* fcb = (const float*)d_in[18];
    const float* iw0 = (const float*)d_in[1];  const float* iw1 = (const float*)d_in[9];
    const float* cw0 = (const float*)d_in[2];  const float* cw1 = (const float*)d_in[10];
    const float* cb0 = (const float*)d_in[3];  const float* cb1 = (const float*)d_in[11];
    const float* al0 = (const float*)d_in[4];  const float* al1 = (const float*)d_in[12];
    const float* db0 = (const float*)d_in[5];  const float* db1 = (const float*)d_in[13];
    const float* Dv0 = (const float*)d_in[6];  const float* Dv1 = (const float*)d_in[14];
    const float* nw0 = (const float*)d_in[7];  const float* nw1 = (const float*)d_in[15];
    const float* ow0 = (const float*)d_in[8];  const float* ow1 = (const float*)d_in[16];

    char* ws = (char*)d_ws;
    size_t off = 0;
    auto alloc = [&](size_t bytes) {
        void* p = ws + off; off += (bytes + 255) & ~(size_t)255; return p;
    };
    unsigned short* xbf   = (unsigned short*)alloc((size_t)NROWS * 512 * 2);
    unsigned short* wbA   = (unsigned short*)alloc((size_t)2 * 2304 * 512 * 2);
    unsigned short* wbOT0 = (unsigned short*)alloc((size_t)1024 * 512 * 2);
    unsigned short* wbOT1 = (unsigned short*)alloc((size_t)1024 * 512 * 2);
    unsigned short* wf    = (unsigned short*)alloc((size_t)512 * 1024 * 2);
    unsigned short* wcomb = (unsigned short*)alloc((size_t)512 * 2048 * 2);
    unsigned short* zx    = (unsigned short*)alloc((size_t)2 * NROWS * NZX * 2);
    unsigned short* xbc   = (unsigned short*)alloc((size_t)2 * NROWS * 1280 * 2);
    float* dtb            = (float*)alloc((size_t)2 * 2048 * 64 * 4);
    float* csb            = (float*)alloc((size_t)2 * 2048 * 64 * 4);
    unsigned short* ybh   = (unsigned short*)alloc((size_t)NROWS * 1024 * 2);
    unsigned short* ybv   = (unsigned short*)alloc((size_t)NROWS * 1024 * 2);

    prep_kernel<<<PB4, 256, 0, stream>>>(x, fcw, iw0, iw1, ow0, ow1, db0, db1,
                                         al0, al1, xbf, wf, wbA, wbOT0, wbOT1,
                                         dtb, csb);
    gemm_big<<<dim3(296, 1, 2), 512, 0, stream>>>(xbf, wbA, zx, wf,
                                                  wbOT0, wbOT1, wcomb,
                                                  cw0, cw1, cb0, cb1, xbc);
    scan_kernel<<<dim3(2048, 2), 256, 0, stream>>>(xbc, dtb, csb,
                                                   Dv0, Dv1, ybh, ybv);
    gate_norm<<<dim3(NROWS, 2), 128, 0, stream>>>(zx, ybh, ybv, nw0, nw1);
    gemm_final2048<<<dim3(64, 8), 256, 0, stream>>>(ybv, ybh, wcomb, fcb, (float*)d_out);
}

// Round 9
// 281.535 us; speedup vs baseline: 1.0422x; 1.0422x over previous
//
#include <hip/hip_runtime.h>

#define NROWS 8192      // 128 sequences * 64 positions
#define NZX   2304      // z (1024) + xBC (1280) columns from in-proj
#define BCS   136       // Bs/Cs LDS row stride (elements, padded)
#define XMS   72        // XsT/Ms LDS row stride (elements, padded)

// prep kernel block ranges (R10 layout)
#define PB0 4096            // cvt x -> xbf
#define PB1 (PB0 + 2048)    // fold_w
#define PB2 (PB1 + 2304)    // cvt in_w (both dirs)
#define PB3 (PB2 + 256)     // cvtT out_w (both dirs)
#define PB4 (PB3 + 512)     // dt_cs (both dirs, 8 heads/block)

typedef __attribute__((ext_vector_type(8))) short bf16x8;
typedef __attribute__((ext_vector_type(4))) float f32x4;

__device__ __forceinline__ float bf2f(unsigned short u) {
    union { unsigned int i; float f; } v; v.i = ((unsigned int)u) << 16; return v.f;
}
// fast bf16 round (half-up): 2 VALU ops
__device__ __forceinline__ unsigned short f2bf(float f) {
    union { float f; unsigned int i; } v; v.f = f;
    return (unsigned short)((v.i + 0x8000u) >> 16);
}

// async global->LDS, 16B per lane; lane's LDS slot must be wave-base + lane*16.
__device__ __forceinline__ void async_lds16(const unsigned short* g, unsigned short* l) {
    __builtin_amdgcn_global_load_lds(
        (const __attribute__((address_space(1))) unsigned int*)g,
        (__attribute__((address_space(3))) unsigned int*)l, 16, 0, 0);
}

// ---------------------------------------------------------------------------
// PREP: all input conversions + dt/cumsum path, block-range dispatched. (R10)
// ---------------------------------------------------------------------------
__global__ __launch_bounds__(256) void prep_kernel(
    const float* __restrict__ x, const float* __restrict__ fcw,
    const float* __restrict__ iw0, const float* __restrict__ iw1,
    const float* __restrict__ ow0, const float* __restrict__ ow1,
    const float* __restrict__ db0, const float* __restrict__ db1,
    const float* __restrict__ al0, const float* __restrict__ al1,
    unsigned short* __restrict__ xbf, unsigned short* __restrict__ wf,
    unsigned short* __restrict__ wbA, unsigned short* __restrict__ wbOT0,
    unsigned short* __restrict__ wbOT1, float* __restrict__ dtbb,
    float* __restrict__ csbb)
{
    __shared__ char sm[37888] __attribute__((aligned(16)));
    const int blk = blockIdx.x, tid = threadIdx.x;
    if (blk < PB0) {
        int i = blk * 256 + tid;
        float4 v = *(const float4*)(x + (size_t)i * 4);
        ushort4 o;
        o.x = f2bf(v.x); o.y = f2bf(v.y); o.z = f2bf(v.z); o.w = f2bf(v.w);
        *(ushort4*)(xbf + (size_t)i * 4) = o;
    } else if (blk < PB1) {
        int idx = (blk - PB0) * 256 + tid;
        int o = idx >> 10, c = idx & 1023;
        int half = c >> 9, cc = c & 511;
        float v = fcw[(size_t)o * 2048 + half * 1024 + cc] +
                  fcw[(size_t)o * 2048 + half * 1024 + 512 + cc];
        wf[idx] = f2bf(v);
    } else if (blk < PB2) {
        int local = blk - PB1;
        int dir = local / 1152;
        int i = (local % 1152) * 256 + tid;
        const float* s = dir ? iw1 : iw0;
        float4 v = *(const float4*)(s + (size_t)i * 4);
        ushort4 o;
        o.x = f2bf(v.x); o.y = f2bf(v.y); o.z = f2bf(v.z); o.w = f2bf(v.w);
        *(ushort4*)(wbA + (size_t)dir * (2304 * 512) + (size_t)i * 4) = o;
    } else if (blk < PB3) {
        float (*T)[65] = (float(*)[65])sm;
        int local = blk - PB2;
        int z = local >> 7, rem = local & 127;
        const float* s = z ? ow1 : ow0;
        unsigned short* d = z ? wbOT1 : wbOT0;
        const int bo = (rem >> 4) * 64, bc = (rem & 15) * 64;
#pragma unroll
        for (int i = 0; i < 16; ++i) {
            int slot = tid + i * 256;
            int r = slot >> 6, c = slot & 63;
            T[r][c] = s[(size_t)(bo + r) * 1024 + bc + c];
        }
        __syncthreads();
#pragma unroll
        for (int i = 0; i < 16; ++i) {
            int slot = tid + i * 256;
            int cr = slot >> 6, oc = slot & 63;
            d[(size_t)(bc + cr) * 512 + bo + oc] = f2bf(T[oc][cr]);
        }
    } else {
        // dt path fp32, both dirs; 256 blocks per dir; block = (seq, 8-head half)
        float (*wsm)[512] = (float(*)[512])sm;                       // 16 KB
        float (*xs)[68]   = (float(*)[68])(sm + 16384);              // 17.4 KB
        float (*dta)[64]  = (float(*)[64])(sm + 16384 + 17408);      // 2 KB
        float (*dtt)[64]  = (float(*)[64])(sm + 16384 + 17408 + 2048);
        int local = blk - PB3;
        const int dir = local >> 8, bxl = local & 255;
        const float* in_w = dir ? iw1 : iw0;
        const float* dt_bias = dir ? db1 : db0;
        const float* A_log = dir ? al1 : al0;
        float* dtb = dtbb + (size_t)dir * 131072;
        float* csb = csbb + (size_t)dir * 131072;
        const int seq = bxl >> 1, hq = bxl & 1;
#pragma unroll
        for (int i = 0; i < 4; ++i) {
            int slot = tid + i * 256;
            int h = slot >> 7, c = (slot & 127) * 4;
            *(float4*)&wsm[h][c] = *(const float4*)(in_w + (size_t)(2304 + hq * 8 + h) * 512 + c);
        }
        const int t = tid & 63, hg = tid >> 6;   // 2 heads per thread
        float acc[2] = {0.f, 0.f};
        for (int c0 = 0; c0 < 512; c0 += 64) {
            __syncthreads();
#pragma unroll
            for (int i = 0; i < 4; ++i) {
                int slot = tid + i * 256;
                int r = slot >> 4, cc = (slot & 15) * 4;
                size_t row = (dir == 0) ? (size_t)seq * 64 + r
                                        : (size_t)(seq >> 6) * 4096 + (size_t)r * 64 + (seq & 63);
                *(float4*)&xs[r][cc] = *(const float4*)(x + row * 512 + c0 + cc);
            }
            __syncthreads();
#pragma unroll
            for (int cc = 0; cc < 64; cc += 4) {
                float4 u4 = *(const float4*)&xs[t][cc];
                const float* w0 = &wsm[hg * 2][c0 + cc];
                const float* w1 = &wsm[hg * 2 + 1][c0 + cc];
                acc[0] += u4.x * w0[0] + u4.y * w0[1] + u4.z * w0[2] + u4.w * w0[3];
                acc[1] += u4.x * w1[0] + u4.y * w1[1] + u4.z * w1[2] + u4.w * w1[3];
            }
        }
#pragma unroll
        for (int hh = 0; hh < 2; ++hh) {
            int hl = hg * 2 + hh;
            int h = hq * 8 + hl;
            float v = acc[hh] + dt_bias[h];
            float dtv = (v > 20.f) ? v : log1pf(__expf(v));
            dtt[hl][t] = dtv;
            dta[hl][t] = dtv * -__expf(A_log[h]);
        }
        __syncthreads();
        if (tid < 8) {
            float run = 0.f;
            int ob = (seq * 16 + hq * 8 + tid) * 64;
            for (int tt = 0; tt < 64; ++tt) {
                run += dta[tid][tt];
                dtb[ob + tt] = dtt[tid][tt];
                csb[ob + tt] = run;
            }
        }
    }
}

// ---------------------------------------------------------------------------
// gemm_big (R14 schedule, best measured): 256x256 tiles, 512 threads
// (8 waves, 2M x 4N), BK=64, double-buffered LDS (128 KiB). 2 phases per
// K-tile, fragments read once per K-tile (B held in regs):
//   phase A: wait vmcnt(2); barrier; stage A0',B0'; read B(all)+A0; 32 MFMA
//   phase B: wait vmcnt(4); barrier; stage B1',A1'; read A1;        32 MFMA
// bx<288: in-proj (M=8192,N=2304,K=512; perm on z=1; XCD-swizzled);
// bx>=288: wcomb halves. xBC panels get the register-resident conv+silu
// epilogue -> xbc; z/wcomb panels store bf16 via granule-rotated WR.
// ---------------------------------------------------------------------------
struct GemmEpi { unsigned short* C; int ldc; int colsub; int conv; };

template<int QA, bool LOADB>
__device__ __forceinline__ void mma_half(
    const unsigned short* Ab, const unsigned short* Bb,
    const int (&aoff)[4], const int (&boff)[2], const int (&kcx)[2],
    bf16x8 (&bv)[2][2][2], f32x4 (&acc)[8][4])
{
    bf16x8 av[4][2];
#pragma unroll
    for (int f = 0; f < 4; ++f)
#pragma unroll
        for (int kh = 0; kh < 2; ++kh)
            av[f][kh] = *(const bf16x8*)(Ab + QA * 8192 + aoff[f] + kcx[kh]);
    if (LOADB) {
#pragma unroll
        for (int h = 0; h < 2; ++h)
#pragma unroll
            for (int g = 0; g < 2; ++g)
#pragma unroll
                for (int kh = 0; kh < 2; ++kh)
                    bv[h][g][kh] = *(const bf16x8*)(Bb + h * 8192 + boff[g] + kcx[kh]);
    }
    __builtin_amdgcn_s_setprio(1);
#pragma unroll
    for (int f = 0; f < 4; ++f)
#pragma unroll
        for (int h = 0; h < 2; ++h)
#pragma unroll
            for (int g = 0; g < 2; ++g)
#pragma unroll
                for (int kh = 0; kh < 2; ++kh)
                    acc[QA * 4 + f][h * 2 + g] = __builtin_amdgcn_mfma_f32_16x16x32_bf16(
                        av[f][kh], bv[h][g][kh], acc[QA * 4 + f][h * 2 + g], 0, 0, 0);
    __builtin_amdgcn_s_setprio(0);
}

__global__ __launch_bounds__(512) void gemm_big(
    const unsigned short* __restrict__ xbf, const unsigned short* __restrict__ wbA,
    unsigned short* __restrict__ zx, const unsigned short* __restrict__ wf,
    const unsigned short* __restrict__ wbOT0, const unsigned short* __restrict__ wbOT1,
    unsigned short* __restrict__ wcomb, const float* __restrict__ cw0,
    const float* __restrict__ cw1, const float* __restrict__ cb0,
    const float* __restrict__ cb1, unsigned short* __restrict__ xbc)
{
    __shared__ unsigned short SMEM[65536] __attribute__((aligned(16)));  // 128 KiB
    unsigned short* AS = SMEM;            // [buf][half][128*64]
    unsigned short* BS = SMEM + 32768;
    const int bx = blockIdx.x, z = blockIdx.z;
    const unsigned short *A, *B;
    int lda, perm, mB, nB;
    GemmEpi epi;
    if (bx < 288) {
        // XCD swizzle: 288 tiles/dir; XCD x owns mt in [4x, 4x+4) x all 9 nt.
        int xcd = bx & 7, l = bx >> 3;
        int cid = xcd * 36 + l;
        int mt = cid / 9, nt = cid - mt * 9;
        mB = mt * 256; nB = nt * 256;
        A = xbf; lda = 512; perm = z;
        B = wbA + (size_t)z * (2304 * 512);
        if (nB >= 1024) { epi.C = xbc + (size_t)z * NROWS * 1280; epi.ldc = 1280; epi.colsub = 1024; epi.conv = 1; }
        else            { epi.C = zx + (size_t)z * NROWS * NZX;  epi.ldc = NZX;  epi.colsub = 0;    epi.conv = 0; }
    } else {
        int t2 = bx - 288;
        mB = (t2 >> 2) * 256; nB = (t2 & 3) * 256;
        A = z ? wf : wf + 512; lda = 1024; perm = 0;
        B = z ? wbOT1 : wbOT0;
        epi.C = z ? wcomb : wcomb + 1024; epi.ldc = 2048; epi.colsub = 0; epi.conv = 0;
    }
    const int tid = threadIdx.x, wave = tid >> 6, lane = tid & 63;
    const int wr = wave >> 2, wc = wave & 3;
    const int lr = lane & 15, lq = lane >> 4;
    // ---- staging pointers (2 issues x 2 halves for A and B)
    const unsigned short* gA[2][2];
    const unsigned short* gB[2][2];
    int ldsSlot[2];
#pragma unroll
    for (int i = 0; i < 2; ++i) {
        int s = tid + i * 512;
        int r = s >> 3, p = s & 7, q = p ^ (r & 7);
        ldsSlot[i] = s * 8;
#pragma unroll
        for (int h = 0; h < 2; ++h) {
            int ar = mB + h * 128 + r;
            if (perm) ar = (ar & ~4095) | ((ar & 63) << 6) | ((ar >> 6) & 63);
            gA[i][h] = A + (size_t)ar * lda + q * 8;
            gB[i][h] = B + (size_t)(nB + h * 128 + r) * 512 + q * 8;
        }
    }
    // ---- fragment LDS offsets
    int aoff[4], boff[2], kcx[2];
#pragma unroll
    for (int f = 0; f < 4; ++f) aoff[f] = (wr * 64 + f * 16 + lr) * 64;
#pragma unroll
    for (int g = 0; g < 2; ++g) boff[g] = (wc * 32 + g * 16 + lr) * 64;
#pragma unroll
    for (int kh = 0; kh < 2; ++kh) kcx[kh] = ((kh * 4 + lq) ^ (lr & 7)) * 8;
    f32x4 acc[8][4];
#pragma unroll
    for (int m = 0; m < 8; ++m)
#pragma unroll
        for (int n = 0; n < 4; ++n) acc[m][n] = (f32x4){0.f, 0.f, 0.f, 0.f};

#define STAGE_A(H, K0, CB) { _Pragma("unroll") \
    for (int i = 0; i < 2; ++i) async_lds16(gA[i][H] + (K0), AS + (CB) * 16384 + (H) * 8192 + ldsSlot[i]); }
#define STAGE_B(H, K0, CB) { _Pragma("unroll") \
    for (int i = 0; i < 2; ++i) async_lds16(gB[i][H] + (K0), BS + (CB) * 16384 + (H) * 8192 + ldsSlot[i]); }

    // ---- prologue: tile 0 into buf0, order A0,B0,B1,A1 (A1 last: phase-B-only)
    STAGE_A(0, 0, 0); STAGE_B(0, 0, 0); STAGE_B(1, 0, 0); STAGE_A(1, 0, 0);
    // ---- main loop: tiles 0..6, each stages tile t+1 into the other buffer
#pragma unroll 1
    for (int t = 0; t < 7; ++t) {
        const int cb = t & 1, nb2 = cb ^ 1, k1 = (t + 1) * 64;
        const unsigned short* Ab = AS + cb * 16384;
        const unsigned short* Bb = BS + cb * 16384;
        bf16x8 bv[2][2][2];
        // phase A: needs A0,B0,B1 of t (A1 of t still in flight)
        asm volatile("s_waitcnt vmcnt(2)" ::: "memory");
        asm volatile("s_barrier" ::: "memory");
        STAGE_A(0, k1, nb2); STAGE_B(0, k1, nb2);
        mma_half<0, true>(Ab, Bb, aoff, boff, kcx, bv, acc);
        // phase B: needs A1 of t (t+1's A0,B0 in flight)
        asm volatile("s_waitcnt vmcnt(4)" ::: "memory");
        asm volatile("s_barrier" ::: "memory");
        STAGE_B(1, k1, nb2); STAGE_A(1, k1, nb2);
        mma_half<1, false>(Ab, Bb, aoff, boff, kcx, bv, acc);
    }
    // ---- tail: tile 7 (buf1), no staging
    {
        const unsigned short* Ab = AS + 16384;
        const unsigned short* Bb = BS + 16384;
        bf16x8 bv[2][2][2];
        asm volatile("s_waitcnt vmcnt(2)" ::: "memory");
        asm volatile("s_barrier" ::: "memory");
        mma_half<0, true>(Ab, Bb, aoff, boff, kcx, bv, acc);
        asm volatile("s_waitcnt vmcnt(0)" ::: "memory");
        asm volatile("s_barrier" ::: "memory");
        mma_half<1, false>(Ab, Bb, aoff, boff, kcx, bv, acc);
    }

    // ---- epilogue. WR scratch in buf0 B-region (tile 7 read buf1; disjoint).
    unsigned short* WR = BS + wave * 1024;   // 16 rows x 64 cols per wave
    const int rsl = (lane + 48) & 63;        // lane reads lane-16 (mod 64)
    if (epi.conv) {
        // conv weights/bias for this wave's 64 cols (4 col-frags c4=qb*2+g)
        float4 wv[4]; float bb[4];
#pragma unroll
        for (int c4 = 0; c4 < 4; ++c4) {
            int col = nB - 1024 + (c4 >> 1) * 128 + wc * 32 + (c4 & 1) * 16 + lr;
            const float* cwp = z ? cw1 : cw0;
            const float* cbp = z ? cb1 : cb0;
            wv[c4] = *(const float4*)(cwp + (size_t)col * 4);
            bb[c4] = cbp[col];
        }
#pragma unroll
        for (int h = 0; h < 2; ++h) {
            float pr1[4], pr2[4], pr3[4];
#pragma unroll
            for (int c4 = 0; c4 < 4; ++c4) { pr1[c4] = 0.f; pr2[c4] = 0.f; pr3[c4] = 0.f; }
#pragma unroll
            for (int f = 0; f < 4; ++f) {
#pragma unroll
                for (int c4 = 0; c4 < 4; ++c4) {
                    float vq[4];
#pragma unroll
                    for (int r = 0; r < 4; ++r) vq[r] = acc[h * 4 + f][c4][r];
                    float rc1 = __shfl(vq[1], rsl);
                    float rc2 = __shfl(vq[2], rsl);
                    float rc3 = __shfl(vq[3], rsl);
                    float u1 = lq ? rc3 : pr3[c4];
                    float u2 = lq ? rc2 : pr2[c4];
                    float u3 = lq ? rc1 : pr1[c4];
                    pr1[c4] = rc1; pr2[c4] = rc2; pr3[c4] = rc3;
                    float y4[4];
                    y4[0] = bb[c4] + wv[c4].w*vq[0] + wv[c4].z*u1    + wv[c4].y*u2    + wv[c4].x*u3;
                    y4[1] = bb[c4] + wv[c4].w*vq[1] + wv[c4].z*vq[0] + wv[c4].y*u1    + wv[c4].x*u2;
                    y4[2] = bb[c4] + wv[c4].w*vq[2] + wv[c4].z*vq[1] + wv[c4].y*vq[0] + wv[c4].x*u1;
                    y4[3] = bb[c4] + wv[c4].w*vq[3] + wv[c4].z*vq[2] + wv[c4].y*vq[1] + wv[c4].x*vq[0];
#pragma unroll
                    for (int r = 0; r < 4; ++r) {
                        float a = y4[r];
                        float s = a / (1.f + __expf(-a));
                        int r16 = lq * 4 + r;
                        int cn = c4 * 16 + lr;
                        int gp = ((cn >> 3) + (r16 >> 1)) & 7;
                        WR[r16 * 64 + gp * 8 + (cn & 7)] = f2bf(s);
                    }
                }
#pragma unroll
                for (int j = 0; j < 2; ++j) {
                    int r16 = j * 8 + (lane >> 3);
                    int gr = lane & 7;
                    int gp = (gr + (r16 >> 1)) & 7;
                    uint4 v = *(const uint4*)(WR + r16 * 64 + gp * 8);
                    int row = mB + h * 128 + wr * 64 + f * 16 + r16;
                    int col = nB - epi.colsub + (gr >> 2) * 128 + wc * 32 + ((gr >> 1) & 1) * 16 + (gr & 1) * 8;
                    *(uint4*)(epi.C + (size_t)row * epi.ldc + col) = v;
                }
            }
        }
    } else {
#pragma unroll
        for (int h = 0; h < 2; ++h)
#pragma unroll
            for (int f = 0; f < 4; ++f) {
#pragma unroll
                for (int c4 = 0; c4 < 4; ++c4)
#pragma unroll
                    for (int r = 0; r < 4; ++r) {
                        int r16 = lq * 4 + r;
                        int cn = c4 * 16 + lr;
                        int gp = ((cn >> 3) + (r16 >> 1)) & 7;
                        WR[r16 * 64 + gp * 8 + (cn & 7)] = f2bf(acc[h * 4 + f][c4][r]);
                    }
#pragma unroll
                for (int j = 0; j < 2; ++j) {
                    int r16 = j * 8 + (lane >> 3);
                    int gr = lane & 7;
                    int gp = (gr + (r16 >> 1)) & 7;
                    uint4 v = *(const uint4*)(WR + r16 * 64 + gp * 8);
                    int row = mB + h * 128 + wr * 64 + f * 16 + r16;
                    int col = nB + (gr >> 2) * 128 + wc * 32 + ((gr >> 1) & 1) * 16 + (gr & 1) * 8;
                    *(uint4*)(epi.C + (size_t)row * epi.ldc + col) = v;
                }
            }
    }
#undef STAGE_A
#undef STAGE_B
}

// ---------------------------------------------------------------------------
// Final GEMM, 128x64 tiles, BK=64 (512 blocks), XCD-swizzled. (R11)
// ---------------------------------------------------------------------------
__global__ __launch_bounds__(256) void gemm_final2048(
    const unsigned short* __restrict__ YV, const unsigned short* __restrict__ YH,
    const unsigned short* __restrict__ W, const float* __restrict__ bias,
    float* __restrict__ C)
{
    __shared__ unsigned short As[128 * 64];
    __shared__ unsigned short Bs[64 * 64];
    const int tid = threadIdx.x, wave = tid >> 6, lane = tid & 63;
    const int did = blockIdx.y * 64 + blockIdx.x;   // 0..511
    const int mB = (did >> 3) * 128, nB = (did & 7) * 64;
    const int lr = lane & 15, lq = lane >> 4;
    int aq[4], agr[4], apr[4];
    unsigned short* lA[4];
    const unsigned short* BgP[2];
    unsigned short* lB[2];
#pragma unroll
    for (int i = 0; i < 4; ++i) {
        int s = tid + i * 256;              // A: 1024 slots
        int r = s >> 3, p = s & 7;
        aq[i] = (p ^ (r & 7)) * 8;
        int gr = mB + r;
        agr[i] = gr;
        apr[i] = (gr & ~4095) | ((gr & 63) << 6) | ((gr >> 6) & 63);
        lA[i] = As + s * 8;
    }
#pragma unroll
    for (int i = 0; i < 2; ++i) {
        int s = tid + i * 256;              // B: 512 slots
        int r = s >> 3, p = s & 7;
        int q = p ^ (r & 7);
        BgP[i] = W + (size_t)(nB + r) * 2048 + q * 8;
        lB[i] = Bs + s * 8;
    }
    const int aswz = lr & 7;
    int arb[2], brb[4];
#pragma unroll
    for (int i = 0; i < 2; ++i) arb[i] = (wave * 32 + i * 16 + lr) * 64;
#pragma unroll
    for (int i = 0; i < 4; ++i) brb[i] = (i * 16 + lr) * 64;
    f32x4 zero4 = {0.f,0.f,0.f,0.f};
    f32x4 acc[2][4] = {{zero4,zero4,zero4,zero4},{zero4,zero4,zero4,zero4}};
    for (int k0 = 0; k0 < 2048; k0 += 64) {
#pragma unroll
        for (int i = 0; i < 4; ++i) {
            int kk = k0 + aq[i];
            const unsigned short* g = (kk < 1024)
                ? YV + (size_t)apr[i] * 1024 + kk
                : YH + (size_t)agr[i] * 1024 + (kk - 1024);
            async_lds16(g, lA[i]);
        }
#pragma unroll
        for (int i = 0; i < 2; ++i) async_lds16(BgP[i] + k0, lB[i]);
        __syncthreads();
#pragma unroll
        for (int kh = 0; kh < 2; ++kh) {
            const int ksw = ((kh * 4 + lq) ^ aswz) * 8;
            bf16x8 a[2], b[4];
#pragma unroll
            for (int i = 0; i < 2; ++i) a[i] = *(const bf16x8*)(As + arb[i] + ksw);
#pragma unroll
            for (int i = 0; i < 4; ++i) b[i] = *(const bf16x8*)(Bs + brb[i] + ksw);
#pragma unroll
            for (int mi = 0; mi < 2; ++mi)
#pragma unroll
                for (int ni = 0; ni < 4; ++ni)
                    acc[mi][ni] = __builtin_amdgcn_mfma_f32_16x16x32_bf16(
                        a[mi], b[ni], acc[mi][ni], 0, 0, 0);
        }
        __syncthreads();
    }
    const int rbase = lq * 4;
#pragma unroll
    for (int mi = 0; mi < 2; ++mi)
#pragma unroll
        for (int ni = 0; ni < 4; ++ni) {
            int col = nB + ni * 16 + lr;
            float bb = bias[col];
#pragma unroll
            for (int r = 0; r < 4; ++r) {
                int row = mB + wave * 32 + mi * 16 + rbase + r;
                C[(size_t)row * 512 + col] = acc[mi][ni][r] + bb;
            }
        }
}

// ---------------------------------------------------------------------------
// G kernel: per (seq, dir) compute G = Cm·Bm^T (64x64, K=128) once, store
// fp32 row-major to Gbuf[(dir*128+seq)*4096 + t*64 + s] (coalesced across
// lr). Grid (128, 2), 256 threads. (R6 version — best measured.)
// ---------------------------------------------------------------------------
__global__ __launch_bounds__(256) void gmat_kernel(
    const unsigned short* __restrict__ xbcb, float* __restrict__ Gbuf)
{
    __shared__ unsigned short Bs[64 * BCS];
    __shared__ unsigned short Cs[64 * BCS];
    const int dir = blockIdx.y, seq = blockIdx.x;
    const unsigned short* base = xbcb + (size_t)dir * NROWS * 1280
                                      + (size_t)seq * 64 * 1280;
    const int tid = threadIdx.x;
    const int lane = tid & 63, wave = tid >> 6;
#pragma unroll
    for (int i = 0; i < 4; ++i) {
        int e = (tid + i * 256) * 8;
        int r = e >> 7, c = e & 127;
        *(uint4*)(Bs + r * BCS + c) = *(const uint4*)(base + (size_t)r * 1280 + 1024 + c);
        *(uint4*)(Cs + r * BCS + c) = *(const uint4*)(base + (size_t)r * 1280 + 1152 + c);
    }
    __syncthreads();
    const int lr = lane & 15, lq = lane >> 4;
    f32x4 zero4 = {0.f,0.f,0.f,0.f};
    f32x4 acc[4] = {zero4, zero4, zero4, zero4};
#pragma unroll
    for (int kt = 0; kt < 4; ++kt) {
        bf16x8 a = *(const bf16x8*)(Cs + (wave * 16 + lr) * BCS + kt * 32 + lq * 8);
#pragma unroll
        for (int ni = 0; ni < 4; ++ni) {
            bf16x8 b = *(const bf16x8*)(Bs + (ni * 16 + lr) * BCS + kt * 32 + lq * 8);
            acc[ni] = __builtin_amdgcn_mfma_f32_16x16x32_bf16(a, b, acc[ni], 0, 0, 0);
        }
    }
    float* G = Gbuf + ((size_t)dir * 128 + seq) * 4096;
#pragma unroll
    for (int ni = 0; ni < 4; ++ni) {
        int s = ni * 16 + lr;
#pragma unroll
        for (int r = 0; r < 4; ++r) {
            int t = wave * 16 + lq * 4 + r;
            G[t * 64 + s] = acc[ni][r];
        }
    }
}

// ---------------------------------------------------------------------------
// Scan (R6 version — best measured): per (seq, head). Triangular skip:
// wave w only loads G and computes exp for fragments ni <= w; zero-fills
// only fragments its own PV MFMAs read; waves 0-1 skip the kt=1 PV chunk.
// Numerically identical to the full computation.
// ---------------------------------------------------------------------------
__global__ __launch_bounds__(256) void scan_kernel(
    const unsigned short* __restrict__ xbcb, const float* __restrict__ Gbuf,
    const float* __restrict__ dtbb, const float* __restrict__ csbb,
    const float* __restrict__ Dv0, const float* __restrict__ Dv1,
    unsigned short* __restrict__ yh, unsigned short* __restrict__ yv)
{
    __shared__ unsigned short XsT[64 * XMS];
    __shared__ unsigned short Ms[64 * XMS];
    __shared__ float dts[64], css[64];
    const int dir = blockIdx.y;
    const unsigned short* xbc = xbcb + (size_t)dir * NROWS * 1280;
    const float* dtb = dtbb + (size_t)dir * 131072;
    const float* csb = csbb + (size_t)dir * 131072;
    const float* Dv = dir ? Dv1 : Dv0;
    unsigned short* y = dir ? yv : yh;
    const int tid = threadIdx.x;
    const int lane = tid & 63, wave = tid >> 6;
    const int seq = blockIdx.x >> 4, h = blockIdx.x & 15;
    if (tid < 64) {
        dts[tid] = dtb[(seq * 16 + h) * 64 + tid];
        css[tid] = csb[(seq * 16 + h) * 64 + tid];
    }
    const unsigned short* base = xbc + (size_t)seq * 64 * 1280;
#pragma unroll
    for (int i = 0; i < 2; ++i) {
        int e = (tid + i * 256) * 8;
        int t = e >> 6, p0 = e & 63;
        uint4 xval = *(const uint4*)(base + (size_t)t * 1280 + h * 64 + p0);
        const unsigned short* xs = (const unsigned short*)&xval;
#pragma unroll
        for (int j = 0; j < 8; ++j) {
            int jl = (j + lane) & 7;
            XsT[(p0 + jl) * XMS + t] = xs[jl];
        }
    }
    const int lr = lane & 15, lq = lane >> 4;
    // load G in the phase-1 output pattern, only fragments ni <= wave
    const float* G = Gbuf + ((size_t)dir * 128 + seq) * 4096;
    f32x4 acc[4];
#pragma unroll
    for (int ni = 0; ni < 4; ++ni) {
        if (ni <= wave) {
            int s = ni * 16 + lr;
#pragma unroll
            for (int r = 0; r < 4; ++r) {
                int t = wave * 16 + lq * 4 + r;
                acc[ni][r] = G[t * 64 + s];
            }
        }
    }
    __syncthreads();
    float css_t[4];
#pragma unroll
    for (int r = 0; r < 4; ++r) css_t[r] = css[wave * 16 + lq * 4 + r];
    const int kmax = (wave < 2) ? 2 : 4;   // frags covered by this wave's PV
#pragma unroll
    for (int ni = 0; ni < 4; ++ni) {
        int s = ni * 16 + lr;
        if (ni <= wave) {
            float cs_s = css[s], dt_s = dts[s];
#pragma unroll
            for (int r = 0; r < 4; ++r) {
                int t = wave * 16 + lq * 4 + r;
                float e = __expf(fminf(css_t[r] - cs_s, 0.f));
                float m = (s <= t) ? acc[ni][r] * e * dt_s : 0.f;
                Ms[t * XMS + s] = f2bf(m);
            }
        } else if (ni < kmax) {
#pragma unroll
            for (int r = 0; r < 4; ++r) {
                int t = wave * 16 + lq * 4 + r;
                Ms[t * XMS + s] = 0;
            }
        }
    }
    __syncthreads();
    f32x4 zero4 = {0.f,0.f,0.f,0.f};
    f32x4 yacc[4] = {zero4, zero4, zero4, zero4};
    const int ktn = (wave < 2) ? 1 : 2;
#pragma unroll
    for (int kt = 0; kt < 2; ++kt) {
        if (kt < ktn) {
            bf16x8 a = *(const bf16x8*)(Ms + (wave * 16 + lr) * XMS + kt * 32 + lq * 8);
#pragma unroll
            for (int ni = 0; ni < 4; ++ni) {
                bf16x8 b = *(const bf16x8*)(XsT + (ni * 16 + lr) * XMS + kt * 32 + lq * 8);
                yacc[ni] = __builtin_amdgcn_mfma_f32_16x16x32_bf16(a, b, yacc[ni], 0, 0, 0);
            }
        }
    }
    const float Dh = Dv[h];
    // stage y[t][p] into Ms rows (own wave band), then coalesced stores
#pragma unroll
    for (int ni = 0; ni < 4; ++ni) {
        int p = ni * 16 + lr;
#pragma unroll
        for (int r = 0; r < 4; ++r) {
            int t = wave * 16 + lq * 4 + r;
            float v = yacc[ni][r] + Dh * bf2f(XsT[p * XMS + t]);
            Ms[t * XMS + p] = f2bf(v);
        }
    }
    __syncthreads();
    unsigned short* yout = y + (size_t)seq * 64 * 1024 + h * 64;
#pragma unroll
    for (int i = 0; i < 2; ++i) {
        int slot = tid + i * 256;      // 512 slots = 64 rows x 8 chunks
        int t = slot >> 3, pc = (slot & 7) * 8;
        uint4 v = *(const uint4*)(Ms + t * XMS + pc);
        *(uint4*)(yout + (size_t)t * 1024 + pc) = v;
    }
}

// ---------------------------------------------------------------------------
// Gate with silu(z) + RMSNorm, dir-merged: grid (8192, 2). (R10)
// ---------------------------------------------------------------------------
__global__ __launch_bounds__(128) void gate_norm(
    const unsigned short* __restrict__ zxb, unsigned short* __restrict__ yh,
    unsigned short* __restrict__ yv, const float* __restrict__ nw0,
    const float* __restrict__ nw1)
{
    const int dir = blockIdx.y;
    const unsigned short* zx = zxb + (size_t)dir * NROWS * NZX;
    unsigned short* y = dir ? yv : yh;
    const float* nw = dir ? nw1 : nw0;
    const int row = blockIdx.x, tid = threadIdx.x;
    uint4 yv4 = *(const uint4*)(y + (size_t)row * 1024 + tid * 8);
    uint4 zv4 = *(const uint4*)(zx + (size_t)row * NZX + tid * 8);
    const unsigned short* ys = (const unsigned short*)&yv4;
    const unsigned short* zs = (const unsigned short*)&zv4;
    float g[8]; float ss = 0.f;
#pragma unroll
    for (int j = 0; j < 8; ++j) {
        float zv = bf2f(zs[j]);
        float gv = bf2f(ys[j]) * (zv / (1.f + __expf(-zv)));
        g[j] = gv; ss += gv * gv;
    }
#pragma unroll
    for (int off = 32; off > 0; off >>= 1) ss += __shfl_xor(ss, off, 64);
    __shared__ float red[2];
    if ((tid & 63) == 0) red[tid >> 6] = ss;
    __syncthreads();
    ss = red[0] + red[1];
    const float scale = rsqrtf(ss * (1.f / 1024.f) + 1e-5f);
    unsigned short out8[8] __attribute__((aligned(16)));
#pragma unroll
    for (int j = 0; j < 8; ++j) out8[j] = f2bf(g[j] * scale * nw[tid * 8 + j]);
    *(uint4*)(y + (size_t)row * 1024 + tid * 8) = *(const uint4*)out8;
}

extern "C" void kernel_launch(void* const* d_in, const int* in_sizes, int n_in,
                              void* d_out, int out_size, void* d_ws, size_t ws_size,
                              hipStream_t stream)
{
    (void)in_sizes; (void)n_in; (void)out_size; (void)ws_size;
    const float* x   = (const float*)d_in[0];
    const float* fcw = (const float*)d_in[17];
    const float* fcb = (const float*)d_in[18];
    const float* iw0 = (const float*)d_in[1];  const float* iw1 = (const float*)d_in[9];
    const float* cw0 = (const float*)d_in[2];  const float* cw1 = (const float*)d_in[10];
    const float* cb0 = (const float*)d_in[3];  const float* cb1 = (const float*)d_in[11];
    const float* al0 = (const float*)d_in[4];  const float* al1 = (const float*)d_in[12];
    const float* db0 = (const float*)d_in[5];  const float* db1 = (const float*)d_in[13];
    const float* Dv0 = (const float*)d_in[6];  const float* Dv1 = (const float*)d_in[14];
    const float* nw0 = (const float*)d_in[7];  const float* nw1 = (const float*)d_in[15];
    const float* ow0 = (const float*)d_in[8];  const float* ow1 = (const float*)d_in[16];

    char* ws = (char*)d_ws;
    size_t off = 0;
    auto alloc = [&](size_t bytes) {
        void* p = ws + off; off += (bytes + 255) & ~(size_t)255; return p;
    };
    unsigned short* xbf   = (unsigned short*)alloc((size_t)NROWS * 512 * 2);
    unsigned short* wbA   = (unsigned short*)alloc((size_t)2 * 2304 * 512 * 2);
    unsigned short* wbOT0 = (unsigned short*)alloc((size_t)1024 * 512 * 2);
    unsigned short* wbOT1 = (unsigned short*)alloc((size_t)1024 * 512 * 2);
    unsigned short* wf    = (unsigned short*)alloc((size_t)512 * 1024 * 2);
    unsigned short* wcomb = (unsigned short*)alloc((size_t)512 * 2048 * 2);
    unsigned short* zx    = (unsigned short*)alloc((size_t)2 * NROWS * NZX * 2);
    unsigned short* xbc   = (unsigned short*)alloc((size_t)2 * NROWS * 1280 * 2);
    float* Gbuf           = (float*)alloc((size_t)2 * 128 * 4096 * 4);
    float* dtb            = (float*)alloc((size_t)2 * 2048 * 64 * 4);
    float* csb            = (float*)alloc((size_t)2 * 2048 * 64 * 4);
    unsigned short* ybh   = (unsigned short*)alloc((size_t)NROWS * 1024 * 2);
    unsigned short* ybv   = (unsigned short*)alloc((size_t)NROWS * 1024 * 2);

    prep_kernel<<<PB4, 256, 0, stream>>>(x, fcw, iw0, iw1, ow0, ow1, db0, db1,
                                         al0, al1, xbf, wf, wbA, wbOT0, wbOT1,
                                         dtb, csb);
    gemm_big<<<dim3(296, 1, 2), 512, 0, stream>>>(xbf, wbA, zx, wf,
                                                  wbOT0, wbOT1, wcomb,
                                                  cw0, cw1, cb0, cb1, xbc);
    gmat_kernel<<<dim3(128, 2), 256, 0, stream>>>(xbc, Gbuf);
    scan_kernel<<<dim3(2048, 2), 256, 0, stream>>>(xbc, Gbuf, dtb, csb,
                                                   Dv0, Dv1, ybh, ybv);
    gate_norm<<<dim3(NROWS, 2), 128, 0, stream>>>(zx, ybh, ybv, nw0, nw1);
    gemm_final2048<<<dim3(64, 8), 256, 0, stream>>>(ybv, ybh, wcomb, fcb, (float*)d_out);
}

// Round 10
// 278.909 us; speedup vs baseline: 1.0520x; 1.0094x over previous
//
#include <hip/hip_runtime.h>

#define NROWS 8192      // 128 sequences * 64 positions
#define NZX   2304      // z (1024) + xBC (1280) columns from in-proj
#define BCS   136       // Bs/Cs LDS row stride (elements, padded)
#define XMS   72        // XsT/Ms LDS row stride (elements, padded)

// prep kernel block ranges (R10 layout)
#define PB0 4096            // cvt x -> xbf
#define PB1 (PB0 + 2048)    // fold_w
#define PB2 (PB1 + 2304)    // cvt in_w (both dirs)
#define PB3 (PB2 + 256)    // cvtT out_w (both dirs)
#define PB4 (PB3 + 512)    // dt_cs (both dirs, 8 heads/block)

typedef __attribute__((ext_vector_type(8))) short bf16x8;
typedef __attribute__((ext_vector_type(4))) float f32x4;

__device__ __forceinline__ float bf2f(unsigned short u) {
    union { unsigned int i; float f; } v; v.i = ((unsigned int)u) << 16; return v.f;
}
// fast bf16 round (half-up): 2 VALU ops
__device__ __forceinline__ unsigned short f2bf(float f) {
    union { float f; unsigned int i; } v; v.f = f;
    return (unsigned short)((v.i + 0x8000u) >> 16);
}

// async global->LDS, 16B per lane; lane's LDS slot must be wave-base + lane*16.
__device__ __forceinline__ void async_lds16(const unsigned short* g, unsigned short* l) {
    __builtin_amdgcn_global_load_lds(
        (const __attribute__((address_space(1))) unsigned int*)g,
        (__attribute__((address_space(3))) unsigned int*)l, 16, 0, 0);
}

// ---------------------------------------------------------------------------
// PREP: all input conversions + dt/cumsum path, block-range dispatched. (R10)
// ---------------------------------------------------------------------------
__global__ __launch_bounds__(256) void prep_kernel(
    const float* __restrict__ x, const float* __restrict__ fcw,
    const float* __restrict__ iw0, const float* __restrict__ iw1,
    const float* __restrict__ ow0, const float* __restrict__ ow1,
    const float* __restrict__ db0, const float* __restrict__ db1,
    const float* __restrict__ al0, const float* __restrict__ al1,
    unsigned short* __restrict__ xbf, unsigned short* __restrict__ wf,
    unsigned short* __restrict__ wbA, unsigned short* __restrict__ wbOT0,
    unsigned short* __restrict__ wbOT1, float* __restrict__ dtbb,
    float* __restrict__ csbb)
{
    __shared__ char sm[37888] __attribute__((aligned(16)));
    const int blk = blockIdx.x, tid = threadIdx.x;
    if (blk < PB0) {
        int i = blk * 256 + tid;
        float4 v = *(const float4*)(x + (size_t)i * 4);
        ushort4 o;
        o.x = f2bf(v.x); o.y = f2bf(v.y); o.z = f2bf(v.z); o.w = f2bf(v.w);
        *(ushort4*)(xbf + (size_t)i * 4) = o;
    } else if (blk < PB1) {
        int idx = (blk - PB0) * 256 + tid;
        int o = idx >> 10, c = idx & 1023;
        int half = c >> 9, cc = c & 511;
        float v = fcw[(size_t)o * 2048 + half * 1024 + cc] +
                  fcw[(size_t)o * 2048 + half * 1024 + 512 + cc];
        wf[idx] = f2bf(v);
    } else if (blk < PB2) {
        int local = blk - PB1;
        int dir = local / 1152;
        int i = (local % 1152) * 256 + tid;
        const float* s = dir ? iw1 : iw0;
        float4 v = *(const float4*)(s + (size_t)i * 4);
        ushort4 o;
        o.x = f2bf(v.x); o.y = f2bf(v.y); o.z = f2bf(v.z); o.w = f2bf(v.w);
        *(ushort4*)(wbA + (size_t)dir * (2304 * 512) + (size_t)i * 4) = o;
    } else if (blk < PB3) {
        float (*T)[65] = (float(*)[65])sm;
        int local = blk - PB2;
        int z = local >> 7, rem = local & 127;
        const float* s = z ? ow1 : ow0;
        unsigned short* d = z ? wbOT1 : wbOT0;
        const int bo = (rem >> 4) * 64, bc = (rem & 15) * 64;
#pragma unroll
        for (int i = 0; i < 16; ++i) {
            int slot = tid + i * 256;
            int r = slot >> 6, c = slot & 63;
            T[r][c] = s[(size_t)(bo + r) * 1024 + bc + c];
        }
        __syncthreads();
#pragma unroll
        for (int i = 0; i < 16; ++i) {
            int slot = tid + i * 256;
            int cr = slot >> 6, oc = slot & 63;
            d[(size_t)(bc + cr) * 512 + bo + oc] = f2bf(T[oc][cr]);
        }
    } else {
        // dt path fp32, both dirs; 256 blocks per dir; block = (seq, 8-head half)
        float (*wsm)[512] = (float(*)[512])sm;                       // 16 KB
        float (*xs)[68]   = (float(*)[68])(sm + 16384);              // 17.4 KB
        float (*dta)[64]  = (float(*)[64])(sm + 16384 + 17408);      // 2 KB
        float (*dtt)[64]  = (float(*)[64])(sm + 16384 + 17408 + 2048);
        int local = blk - PB3;
        const int dir = local >> 8, bxl = local & 255;
        const float* in_w = dir ? iw1 : iw0;
        const float* dt_bias = dir ? db1 : db0;
        const float* A_log = dir ? al1 : al0;
        float* dtb = dtbb + (size_t)dir * 131072;
        float* csb = csbb + (size_t)dir * 131072;
        const int seq = bxl >> 1, hq = bxl & 1;
#pragma unroll
        for (int i = 0; i < 4; ++i) {
            int slot = tid + i * 256;
            int h = slot >> 7, c = (slot & 127) * 4;
            *(float4*)&wsm[h][c] = *(const float4*)(in_w + (size_t)(2304 + hq * 8 + h) * 512 + c);
        }
        const int t = tid & 63, hg = tid >> 6;   // 2 heads per thread
        float acc[2] = {0.f, 0.f};
        for (int c0 = 0; c0 < 512; c0 += 64) {
            __syncthreads();
#pragma unroll
            for (int i = 0; i < 4; ++i) {
                int slot = tid + i * 256;
                int r = slot >> 4, cc = (slot & 15) * 4;
                size_t row = (dir == 0) ? (size_t)seq * 64 + r
                                        : (size_t)(seq >> 6) * 4096 + (size_t)r * 64 + (seq & 63);
                *(float4*)&xs[r][cc] = *(const float4*)(x + row * 512 + c0 + cc);
            }
            __syncthreads();
#pragma unroll
            for (int cc = 0; cc < 64; cc += 4) {
                float4 u4 = *(const float4*)&xs[t][cc];
                const float* w0 = &wsm[hg * 2][c0 + cc];
                const float* w1 = &wsm[hg * 2 + 1][c0 + cc];
                acc[0] += u4.x * w0[0] + u4.y * w0[1] + u4.z * w0[2] + u4.w * w0[3];
                acc[1] += u4.x * w1[0] + u4.y * w1[1] + u4.z * w1[2] + u4.w * w1[3];
            }
        }
#pragma unroll
        for (int hh = 0; hh < 2; ++hh) {
            int hl = hg * 2 + hh;
            int h = hq * 8 + hl;
            float v = acc[hh] + dt_bias[h];
            float dtv = (v > 20.f) ? v : log1pf(__expf(v));
            dtt[hl][t] = dtv;
            dta[hl][t] = dtv * -__expf(A_log[h]);
        }
        __syncthreads();
        if (tid < 8) {
            float run = 0.f;
            int ob = (seq * 16 + hq * 8 + tid) * 64;
            for (int tt = 0; tt < 64; ++tt) {
                run += dta[tid][tt];
                dtb[ob + tt] = dtt[tid][tt];
                csb[ob + tt] = run;
            }
        }
    }
}

// ---------------------------------------------------------------------------
// gemm_big (R18): 256x256 tiles, 512 threads (8 waves, 2M x 4N), BK=64,
// SINGLE-buffer LDS (64 KiB -> 2 blocks/CU, 4 waves/SIMD) with in-place
// quarter staging. Fragments read once per K-tile (B held in regs):
//   phase A: vmcnt(0); barrier; stage A1(t);           read B0,B1,A0(t); 32 MFMA
//   phase B: vmcnt(0); barrier; stage A0,B0,B1(t+1);   read A1(t);       32 MFMA
// Overwrite safety: a quarter's last reader finished before the barrier
// that precedes its restaging (barrier lockstep). TLP across the 2
// co-resident blocks hides the vmcnt drains (m97 regime).
// bx<288: in-proj (XCD-swizzled); bx>=288: wcomb halves. xBC panels get the
// register-resident conv+silu epilogue -> xbc.
// ---------------------------------------------------------------------------
struct GemmEpi { unsigned short* C; int ldc; int colsub; int conv; };

template<int QA, bool LOADB>
__device__ __forceinline__ void mma_half(
    const unsigned short* Ab, const unsigned short* Bb,
    const int (&aoff)[4], const int (&boff)[2], const int (&kcx)[2],
    bf16x8 (&bv)[2][2][2], f32x4 (&acc)[8][4])
{
    bf16x8 av[4][2];
#pragma unroll
    for (int f = 0; f < 4; ++f)
#pragma unroll
        for (int kh = 0; kh < 2; ++kh)
            av[f][kh] = *(const bf16x8*)(Ab + QA * 8192 + aoff[f] + kcx[kh]);
    if (LOADB) {
#pragma unroll
        for (int h = 0; h < 2; ++h)
#pragma unroll
            for (int g = 0; g < 2; ++g)
#pragma unroll
                for (int kh = 0; kh < 2; ++kh)
                    bv[h][g][kh] = *(const bf16x8*)(Bb + h * 8192 + boff[g] + kcx[kh]);
    }
    __builtin_amdgcn_s_setprio(1);
#pragma unroll
    for (int f = 0; f < 4; ++f)
#pragma unroll
        for (int h = 0; h < 2; ++h)
#pragma unroll
            for (int g = 0; g < 2; ++g)
#pragma unroll
                for (int kh = 0; kh < 2; ++kh)
                    acc[QA * 4 + f][h * 2 + g] = __builtin_amdgcn_mfma_f32_16x16x32_bf16(
                        av[f][kh], bv[h][g][kh], acc[QA * 4 + f][h * 2 + g], 0, 0, 0);
    __builtin_amdgcn_s_setprio(0);
}

__global__ __launch_bounds__(512) void gemm_big(
    const unsigned short* __restrict__ xbf, const unsigned short* __restrict__ wbA,
    unsigned short* __restrict__ zx, const unsigned short* __restrict__ wf,
    const unsigned short* __restrict__ wbOT0, const unsigned short* __restrict__ wbOT1,
    unsigned short* __restrict__ wcomb, const float* __restrict__ cw0,
    const float* __restrict__ cw1, const float* __restrict__ cb0,
    const float* __restrict__ cb1, unsigned short* __restrict__ xbc)
{
    __shared__ unsigned short SMEM[32768] __attribute__((aligned(16)));  // 64 KiB
    unsigned short* AS = SMEM;            // [A0: 0..8192) [A1: 8192..16384)
    unsigned short* BS = SMEM + 16384;    // [B0: 0..8192) [B1: 8192..16384)
    const int bx = blockIdx.x, z = blockIdx.z;
    const unsigned short *A, *B;
    int lda, perm, mB, nB;
    GemmEpi epi;
    if (bx < 288) {
        // XCD swizzle: 288 tiles/dir; XCD x owns mt in [4x, 4x+4) x all 9 nt.
        int xcd = bx & 7, l = bx >> 3;
        int cid = xcd * 36 + l;
        int mt = cid / 9, nt = cid - mt * 9;
        mB = mt * 256; nB = nt * 256;
        A = xbf; lda = 512; perm = z;
        B = wbA + (size_t)z * (2304 * 512);
        if (nB >= 1024) { epi.C = xbc + (size_t)z * NROWS * 1280; epi.ldc = 1280; epi.colsub = 1024; epi.conv = 1; }
        else            { epi.C = zx + (size_t)z * NROWS * NZX;  epi.ldc = NZX;  epi.colsub = 0;    epi.conv = 0; }
    } else {
        int t2 = bx - 288;
        mB = (t2 >> 2) * 256; nB = (t2 & 3) * 256;
        A = z ? wf : wf + 512; lda = 1024; perm = 0;
        B = z ? wbOT1 : wbOT0;
        epi.C = z ? wcomb : wcomb + 1024; epi.ldc = 2048; epi.colsub = 0; epi.conv = 0;
    }
    const int tid = threadIdx.x, wave = tid >> 6, lane = tid & 63;
    const int wr = wave >> 2, wc = wave & 3;
    const int lr = lane & 15, lq = lane >> 4;
    // ---- staging pointers (2 issues x 2 halves for A and B)
    const unsigned short* gA[2][2];
    const unsigned short* gB[2][2];
    int ldsSlot[2];
#pragma unroll
    for (int i = 0; i < 2; ++i) {
        int s = tid + i * 512;
        int r = s >> 3, p = s & 7, q = p ^ (r & 7);
        ldsSlot[i] = s * 8;
#pragma unroll
        for (int h = 0; h < 2; ++h) {
            int ar = mB + h * 128 + r;
            if (perm) ar = (ar & ~4095) | ((ar & 63) << 6) | ((ar >> 6) & 63);
            gA[i][h] = A + (size_t)ar * lda + q * 8;
            gB[i][h] = B + (size_t)(nB + h * 128 + r) * 512 + q * 8;
        }
    }
    // ---- fragment LDS offsets
    int aoff[4], boff[2], kcx[2];
#pragma unroll
    for (int f = 0; f < 4; ++f) aoff[f] = (wr * 64 + f * 16 + lr) * 64;
#pragma unroll
    for (int g = 0; g < 2; ++g) boff[g] = (wc * 32 + g * 16 + lr) * 64;
#pragma unroll
    for (int kh = 0; kh < 2; ++kh) kcx[kh] = ((kh * 4 + lq) ^ (lr & 7)) * 8;
    f32x4 acc[8][4];
#pragma unroll
    for (int m = 0; m < 8; ++m)
#pragma unroll
        for (int n = 0; n < 4; ++n) acc[m][n] = (f32x4){0.f, 0.f, 0.f, 0.f};

#define STAGE_A(H, K0) { _Pragma("unroll") \
    for (int i = 0; i < 2; ++i) async_lds16(gA[i][H] + (K0), AS + (H) * 8192 + ldsSlot[i]); }
#define STAGE_B(H, K0) { _Pragma("unroll") \
    for (int i = 0; i < 2; ++i) async_lds16(gB[i][H] + (K0), BS + (H) * 8192 + ldsSlot[i]); }

    // ---- prologue: A0,B0,B1 of tile 0 (A1(0) staged in phase A of t=0)
    STAGE_A(0, 0); STAGE_B(0, 0); STAGE_B(1, 0);
    // ---- main loop, single buffer, in-place quarter staging
#pragma unroll 1
    for (int t = 0; t < 8; ++t) {
        const int k0 = t * 64, k1 = k0 + 64;
        bf16x8 bv[2][2][2];
        // phase A: needs A0,B0,B1 of t (staged one phase earlier)
        asm volatile("s_waitcnt vmcnt(0)" ::: "memory");
        asm volatile("s_barrier" ::: "memory");
        STAGE_A(1, k0);                          // A1 of t (A1(t-1) dead)
        mma_half<0, true>(AS, BS, aoff, boff, kcx, bv, acc);
        // phase B: needs A1 of t
        asm volatile("s_waitcnt vmcnt(0)" ::: "memory");
        asm volatile("s_barrier" ::: "memory");
        if (t < 7) { STAGE_A(0, k1); STAGE_B(0, k1); STAGE_B(1, k1); }
        mma_half<1, false>(AS, BS, aoff, boff, kcx, bv, acc);
    }

    // ---- epilogue. WR scratch in B0 quarter (post-loop reads touch A1 only;
    // any wave in the epilogue passed pB(7)'s barrier => all B0 reads done).
    unsigned short* WR = BS + wave * 1024;   // 16 rows x 64 cols per wave
    const int rsl = (lane + 48) & 63;        // lane reads lane-16 (mod 64)
    if (epi.conv) {
        // conv weights/bias for this wave's 64 cols (4 col-frags c4=qb*2+g)
        float4 wv[4]; float bb[4];
#pragma unroll
        for (int c4 = 0; c4 < 4; ++c4) {
            int col = nB - 1024 + (c4 >> 1) * 128 + wc * 32 + (c4 & 1) * 16 + lr;
            const float* cwp = z ? cw1 : cw0;
            const float* cbp = z ? cb1 : cb0;
            wv[c4] = *(const float4*)(cwp + (size_t)col * 4);
            bb[c4] = cbp[col];
        }
#pragma unroll
        for (int h = 0; h < 2; ++h) {
            float pr1[4], pr2[4], pr3[4];
#pragma unroll
            for (int c4 = 0; c4 < 4; ++c4) { pr1[c4] = 0.f; pr2[c4] = 0.f; pr3[c4] = 0.f; }
#pragma unroll
            for (int f = 0; f < 4; ++f) {
#pragma unroll
                for (int c4 = 0; c4 < 4; ++c4) {
                    float vq[4];
#pragma unroll
                    for (int r = 0; r < 4; ++r) vq[r] = acc[h * 4 + f][c4][r];
                    float rc1 = __shfl(vq[1], rsl);
                    float rc2 = __shfl(vq[2], rsl);
                    float rc3 = __shfl(vq[3], rsl);
                    float u1 = lq ? rc3 : pr3[c4];
                    float u2 = lq ? rc2 : pr2[c4];
                    float u3 = lq ? rc1 : pr1[c4];
                    pr1[c4] = rc1; pr2[c4] = rc2; pr3[c4] = rc3;
                    float y4[4];
                    y4[0] = bb[c4] + wv[c4].w*vq[0] + wv[c4].z*u1    + wv[c4].y*u2    + wv[c4].x*u3;
                    y4[1] = bb[c4] + wv[c4].w*vq[1] + wv[c4].z*vq[0] + wv[c4].y*u1    + wv[c4].x*u2;
                    y4[2] = bb[c4] + wv[c4].w*vq[2] + wv[c4].z*vq[1] + wv[c4].y*vq[0] + wv[c4].x*u1;
                    y4[3] = bb[c4] + wv[c4].w*vq[3] + wv[c4].z*vq[2] + wv[c4].y*vq[1] + wv[c4].x*vq[0];
#pragma unroll
                    for (int r = 0; r < 4; ++r) {
                        float a = y4[r];
                        float s = a / (1.f + __expf(-a));
                        int r16 = lq * 4 + r;
                        int cn = c4 * 16 + lr;
                        int gp = ((cn >> 3) + (r16 >> 1)) & 7;
                        WR[r16 * 64 + gp * 8 + (cn & 7)] = f2bf(s);
                    }
                }
#pragma unroll
                for (int j = 0; j < 2; ++j) {
                    int r16 = j * 8 + (lane >> 3);
                    int gr = lane & 7;
                    int gp = (gr + (r16 >> 1)) & 7;
                    uint4 v = *(const uint4*)(WR + r16 * 64 + gp * 8);
                    int row = mB + h * 128 + wr * 64 + f * 16 + r16;
                    int col = nB - epi.colsub + (gr >> 2) * 128 + wc * 32 + ((gr >> 1) & 1) * 16 + (gr & 1) * 8;
                    *(uint4*)(epi.C + (size_t)row * epi.ldc + col) = v;
                }
            }
        }
    } else {
#pragma unroll
        for (int h = 0; h < 2; ++h)
#pragma unroll
            for (int f = 0; f < 4; ++f) {
#pragma unroll
                for (int c4 = 0; c4 < 4; ++c4)
#pragma unroll
                    for (int r = 0; r < 4; ++r) {
                        int r16 = lq * 4 + r;
                        int cn = c4 * 16 + lr;
                        int gp = ((cn >> 3) + (r16 >> 1)) & 7;
                        WR[r16 * 64 + gp * 8 + (cn & 7)] = f2bf(acc[h * 4 + f][c4][r]);
                    }
#pragma unroll
                for (int j = 0; j < 2; ++j) {
                    int r16 = j * 8 + (lane >> 3);
                    int gr = lane & 7;
                    int gp = (gr + (r16 >> 1)) & 7;
                    uint4 v = *(const uint4*)(WR + r16 * 64 + gp * 8);
                    int row = mB + h * 128 + wr * 64 + f * 16 + r16;
                    int col = nB + (gr >> 2) * 128 + wc * 32 + ((gr >> 1) & 1) * 16 + (gr & 1) * 8;
                    *(uint4*)(epi.C + (size_t)row * epi.ldc + col) = v;
                }
            }
    }
#undef STAGE_A
#undef STAGE_B
}

// ---------------------------------------------------------------------------
// Final GEMM, 128x64 tiles, BK=64 (512 blocks), XCD-swizzled. (R11)
// ---------------------------------------------------------------------------
__global__ __launch_bounds__(256) void gemm_final2048(
    const unsigned short* __restrict__ YV, const unsigned short* __restrict__ YH,
    const unsigned short* __restrict__ W, const float* __restrict__ bias,
    float* __restrict__ C)
{
    __shared__ unsigned short As[128 * 64];
    __shared__ unsigned short Bs[64 * 64];
    const int tid = threadIdx.x, wave = tid >> 6, lane = tid & 63;
    const int did = blockIdx.y * 64 + blockIdx.x;   // 0..511
    const int mB = (did >> 3) * 128, nB = (did & 7) * 64;
    const int lr = lane & 15, lq = lane >> 4;
    int aq[4], agr[4], apr[4];
    unsigned short* lA[4];
    const unsigned short* BgP[2];
    unsigned short* lB[2];
#pragma unroll
    for (int i = 0; i < 4; ++i) {
        int s = tid + i * 256;              // A: 1024 slots
        int r = s >> 3, p = s & 7;
        aq[i] = (p ^ (r & 7)) * 8;
        int gr = mB + r;
        agr[i] = gr;
        apr[i] = (gr & ~4095) | ((gr & 63) << 6) | ((gr >> 6) & 63);
        lA[i] = As + s * 8;
    }
#pragma unroll
    for (int i = 0; i < 2; ++i) {
        int s = tid + i * 256;              // B: 512 slots
        int r = s >> 3, p = s & 7;
        int q = p ^ (r & 7);
        BgP[i] = W + (size_t)(nB + r) * 2048 + q * 8;
        lB[i] = Bs + s * 8;
    }
    const int aswz = lr & 7;
    int arb[2], brb[4];
#pragma unroll
    for (int i = 0; i < 2; ++i) arb[i] = (wave * 32 + i * 16 + lr) * 64;
#pragma unroll
    for (int i = 0; i < 4; ++i) brb[i] = (i * 16 + lr) * 64;
    f32x4 zero4 = {0.f,0.f,0.f,0.f};
    f32x4 acc[2][4] = {{zero4,zero4,zero4,zero4},{zero4,zero4,zero4,zero4}};
    for (int k0 = 0; k0 < 2048; k0 += 64) {
#pragma unroll
        for (int i = 0; i < 4; ++i) {
            int kk = k0 + aq[i];
            const unsigned short* g = (kk < 1024)
                ? YV + (size_t)apr[i] * 1024 + kk
                : YH + (size_t)agr[i] * 1024 + (kk - 1024);
            async_lds16(g, lA[i]);
        }
#pragma unroll
        for (int i = 0; i < 2; ++i) async_lds16(BgP[i] + k0, lB[i]);
        __syncthreads();
#pragma unroll
        for (int kh = 0; kh < 2; ++kh) {
            const int ksw = ((kh * 4 + lq) ^ aswz) * 8;
            bf16x8 a[2], b[4];
#pragma unroll
            for (int i = 0; i < 2; ++i) a[i] = *(const bf16x8*)(As + arb[i] + ksw);
#pragma unroll
            for (int i = 0; i < 4; ++i) b[i] = *(const bf16x8*)(Bs + brb[i] + ksw);
#pragma unroll
            for (int mi = 0; mi < 2; ++mi)
#pragma unroll
                for (int ni = 0; ni < 4; ++ni)
                    acc[mi][ni] = __builtin_amdgcn_mfma_f32_16x16x32_bf16(
                        a[mi], b[ni], acc[mi][ni], 0, 0, 0);
        }
        __syncthreads();
    }
    const int rbase = lq * 4;
#pragma unroll
    for (int mi = 0; mi < 2; ++mi)
#pragma unroll
        for (int ni = 0; ni < 4; ++ni) {
            int col = nB + ni * 16 + lr;
            float bb = bias[col];
#pragma unroll
            for (int r = 0; r < 4; ++r) {
                int row = mB + wave * 32 + mi * 16 + rbase + r;
                C[(size_t)row * 512 + col] = acc[mi][ni][r] + bb;
            }
        }
}

// ---------------------------------------------------------------------------
// G kernel: per (seq, dir) compute G = Cm·Bm^T (64x64, K=128) once, store
// fp32 row-major to Gbuf[(dir*128+seq)*4096 + t*64 + s] (coalesced across
// lr). Grid (128, 2), 256 threads. (R6 version — best measured.)
// ---------------------------------------------------------------------------
__global__ __launch_bounds__(256) void gmat_kernel(
    const unsigned short* __restrict__ xbcb, float* __restrict__ Gbuf)
{
    __shared__ unsigned short Bs[64 * BCS];
    __shared__ unsigned short Cs[64 * BCS];
    const int dir = blockIdx.y, seq = blockIdx.x;
    const unsigned short* base = xbcb + (size_t)dir * NROWS * 1280
                                      + (size_t)seq * 64 * 1280;
    const int tid = threadIdx.x;
    const int lane = tid & 63, wave = tid >> 6;
#pragma unroll
    for (int i = 0; i < 4; ++i) {
        int e = (tid + i * 256) * 8;
        int r = e >> 7, c = e & 127;
        *(uint4*)(Bs + r * BCS + c) = *(const uint4*)(base + (size_t)r * 1280 + 1024 + c);
        *(uint4*)(Cs + r * BCS + c) = *(const uint4*)(base + (size_t)r * 1280 + 1152 + c);
    }
    __syncthreads();
    const int lr = lane & 15, lq = lane >> 4;
    f32x4 zero4 = {0.f,0.f,0.f,0.f};
    f32x4 acc[4] = {zero4, zero4, zero4, zero4};
#pragma unroll
    for (int kt = 0; kt < 4; ++kt) {
        bf16x8 a = *(const bf16x8*)(Cs + (wave * 16 + lr) * BCS + kt * 32 + lq * 8);
#pragma unroll
        for (int ni = 0; ni < 4; ++ni) {
            bf16x8 b = *(const bf16x8*)(Bs + (ni * 16 + lr) * BCS + kt * 32 + lq * 8);
            acc[ni] = __builtin_amdgcn_mfma_f32_16x16x32_bf16(a, b, acc[ni], 0, 0, 0);
        }
    }
    float* G = Gbuf + ((size_t)dir * 128 + seq) * 4096;
#pragma unroll
    for (int ni = 0; ni < 4; ++ni) {
        int s = ni * 16 + lr;
#pragma unroll
        for (int r = 0; r < 4; ++r) {
            int t = wave * 16 + lq * 4 + r;
            G[t * 64 + s] = acc[ni][r];
        }
    }
}

// ---------------------------------------------------------------------------
// Scan (R6 version — best measured): per (seq, head). Triangular skip:
// wave w only loads G and computes exp for fragments ni <= w; zero-fills
// only fragments its own PV MFMAs read; waves 0-1 skip the kt=1 PV chunk.
// Numerically identical to the full computation.
// ---------------------------------------------------------------------------
__global__ __launch_bounds__(256) void scan_kernel(
    const unsigned short* __restrict__ xbcb, const float* __restrict__ Gbuf,
    const float* __restrict__ dtbb, const float* __restrict__ csbb,
    const float* __restrict__ Dv0, const float* __restrict__ Dv1,
    unsigned short* __restrict__ yh, unsigned short* __restrict__ yv)
{
    __shared__ unsigned short XsT[64 * XMS];
    __shared__ unsigned short Ms[64 * XMS];
    __shared__ float dts[64], css[64];
    const int dir = blockIdx.y;
    const unsigned short* xbc = xbcb + (size_t)dir * NROWS * 1280;
    const float* dtb = dtbb + (size_t)dir * 131072;
    const float* csb = csbb + (size_t)dir * 131072;
    const float* Dv = dir ? Dv1 : Dv0;
    unsigned short* y = dir ? yv : yh;
    const int tid = threadIdx.x;
    const int lane = tid & 63, wave = tid >> 6;
    const int seq = blockIdx.x >> 4, h = blockIdx.x & 15;
    if (tid < 64) {
        dts[tid] = dtb[(seq * 16 + h) * 64 + tid];
        css[tid] = csb[(seq * 16 + h) * 64 + tid];
    }
    const unsigned short* base = xbc + (size_t)seq * 64 * 1280;
#pragma unroll
    for (int i = 0; i < 2; ++i) {
        int e = (tid + i * 256) * 8;
        int t = e >> 6, p0 = e & 63;
        uint4 xval = *(const uint4*)(base + (size_t)t * 1280 + h * 64 + p0);
        const unsigned short* xs = (const unsigned short*)&xval;
#pragma unroll
        for (int j = 0; j < 8; ++j) {
            int jl = (j + lane) & 7;
            XsT[(p0 + jl) * XMS + t] = xs[jl];
        }
    }
    const int lr = lane & 15, lq = lane >> 4;
    // load G in the phase-1 output pattern, only fragments ni <= wave
    const float* G = Gbuf + ((size_t)dir * 128 + seq) * 4096;
    f32x4 acc[4];
#pragma unroll
    for (int ni = 0; ni < 4; ++ni) {
        if (ni <= wave) {
            int s = ni * 16 + lr;
#pragma unroll
            for (int r = 0; r < 4; ++r) {
                int t = wave * 16 + lq * 4 + r;
                acc[ni][r] = G[t * 64 + s];
            }
        }
    }
    __syncthreads();
    float css_t[4];
#pragma unroll
    for (int r = 0; r < 4; ++r) css_t[r] = css[wave * 16 + lq * 4 + r];
    const int kmax = (wave < 2) ? 2 : 4;   // frags covered by this wave's PV
#pragma unroll
    for (int ni = 0; ni < 4; ++ni) {
        int s = ni * 16 + lr;
        if (ni <= wave) {
            float cs_s = css[s], dt_s = dts[s];
#pragma unroll
            for (int r = 0; r < 4; ++r) {
                int t = wave * 16 + lq * 4 + r;
                float e = __expf(fminf(css_t[r] - cs_s, 0.f));
                float m = (s <= t) ? acc[ni][r] * e * dt_s : 0.f;
                Ms[t * XMS + s] = f2bf(m);
            }
        } else if (ni < kmax) {
#pragma unroll
            for (int r = 0; r < 4; ++r) {
                int t = wave * 16 + lq * 4 + r;
                Ms[t * XMS + s] = 0;
            }
        }
    }
    __syncthreads();
    f32x4 zero4 = {0.f,0.f,0.f,0.f};
    f32x4 yacc[4] = {zero4, zero4, zero4, zero4};
    const int ktn = (wave < 2) ? 1 : 2;
#pragma unroll
    for (int kt = 0; kt < 2; ++kt) {
        if (kt < ktn) {
            bf16x8 a = *(const bf16x8*)(Ms + (wave * 16 + lr) * XMS + kt * 32 + lq * 8);
#pragma unroll
            for (int ni = 0; ni < 4; ++ni) {
                bf16x8 b = *(const bf16x8*)(XsT + (ni * 16 + lr) * XMS + kt * 32 + lq * 8);
                yacc[ni] = __builtin_amdgcn_mfma_f32_16x16x32_bf16(a, b, yacc[ni], 0, 0, 0);
            }
        }
    }
    const float Dh = Dv[h];
    // stage y[t][p] into Ms rows (own wave band), then coalesced stores
#pragma unroll
    for (int ni = 0; ni < 4; ++ni) {
        int p = ni * 16 + lr;
#pragma unroll
        for (int r = 0; r < 4; ++r) {
            int t = wave * 16 + lq * 4 + r;
            float v = yacc[ni][r] + Dh * bf2f(XsT[p * XMS + t]);
            Ms[t * XMS + p] = f2bf(v);
        }
    }
    __syncthreads();
    unsigned short* yout = y + (size_t)seq * 64 * 1024 + h * 64;
#pragma unroll
    for (int i = 0; i < 2; ++i) {
        int slot = tid + i * 256;      // 512 slots = 64 rows x 8 chunks
        int t = slot >> 3, pc = (slot & 7) * 8;
        uint4 v = *(const uint4*)(Ms + t * XMS + pc);
        *(uint4*)(yout + (size_t)t * 1024 + pc) = v;
    }
}

// ---------------------------------------------------------------------------
// Gate with silu(z) + RMSNorm, dir-merged: grid (8192, 2). (R10)
// ---------------------------------------------------------------------------
__global__ __launch_bounds__(128) void gate_norm(
    const unsigned short* __restrict__ zxb, unsigned short* __restrict__ yh,
    unsigned short* __restrict__ yv, const float* __restrict__ nw0,
    const float* __restrict__ nw1)
{
    const int dir = blockIdx.y;
    const unsigned short* zx = zxb + (size_t)dir * NROWS * NZX;
    unsigned short* y = dir ? yv : yh;
    const float* nw = dir ? nw1 : nw0;
    const int row = blockIdx.x, tid = threadIdx.x;
    uint4 yv4 = *(const uint4*)(y + (size_t)row * 1024 + tid * 8);
    uint4 zv4 = *(const uint4*)(zx + (size_t)row * NZX + tid * 8);
    const unsigned short* ys = (const unsigned short*)&yv4;
    const unsigned short* zs = (const unsigned short*)&zv4;
    float g[8]; float ss = 0.f;
#pragma unroll
    for (int j = 0; j < 8; ++j) {
        float zv = bf2f(zs[j]);
        float gv = bf2f(ys[j]) * (zv / (1.f + __expf(-zv)));
        g[j] = gv; ss += gv * gv;
    }
#pragma unroll
    for (int off = 32; off > 0; off >>= 1) ss += __shfl_xor(ss, off, 64);
    __shared__ float red[2];
    if ((tid & 63) == 0) red[tid >> 6] = ss;
    __syncthreads();
    ss = red[0] + red[1];
    const float scale = rsqrtf(ss * (1.f / 1024.f) + 1e-5f);
    unsigned short out8[8] __attribute__((aligned(16)));
#pragma unroll
    for (int j = 0; j < 8; ++j) out8[j] = f2bf(g[j] * scale * nw[tid * 8 + j]);
    *(uint4*)(y + (size_t)row * 1024 + tid * 8) = *(const uint4*)out8;
}

extern "C" void kernel_launch(void* const* d_in, const int* in_sizes, int n_in,
                              void* d_out, int out_size, void* d_ws, size_t ws_size,
                              hipStream_t stream)
{
    (void)in_sizes; (void)n_in; (void)out_size; (void)ws_size;
    const float* x   = (const float*)d_in[0];
    const float* fcw = (const float*)d_in[17];
    const float* fcb = (const float*)d_in[18];
    const float* iw0 = (const float*)d_in[1];  const float* iw1 = (const float*)d_in[9];
    const float* cw0 = (const float*)d_in[2];  const float* cw1 = (const float*)d_in[10];
    const float* cb0 = (const float*)d_in[3];  const float* cb1 = (const float*)d_in[11];
    const float* al0 = (const float*)d_in[4];  const float* al1 = (const float*)d_in[12];
    const float* db0 = (const float*)d_in[5];  const float* db1 = (const float*)d_in[13];
    const float* Dv0 = (const float*)d_in[6];  const float* Dv1 = (const float*)d_in[14];
    const float* nw0 = (const float*)d_in[7];  const float* nw1 = (const float*)d_in[15];
    const float* ow0 = (const float*)d_in[8];  const float* ow1 = (const float*)d_in[16];

    char* ws = (char*)d_ws;
    size_t off = 0;
    auto alloc = [&](size_t bytes) {
        void* p = ws + off; off += (bytes + 255) & ~(size_t)255; return p;
    };
    unsigned short* xbf   = (unsigned short*)alloc((size_t)NROWS * 512 * 2);
    unsigned short* wbA   = (unsigned short*)alloc((size_t)2 * 2304 * 512 * 2);
    unsigned short* wbOT0 = (unsigned short*)alloc((size_t)1024 * 512 * 2);
    unsigned short* wbOT1 = (unsigned short*)alloc((size_t)1024 * 512 * 2);
    unsigned short* wf    = (unsigned short*)alloc((size_t)512 * 1024 * 2);
    unsigned short* wcomb = (unsigned short*)alloc((size_t)512 * 2048 * 2);
    unsigned short* zx    = (unsigned short*)alloc((size_t)2 * NROWS * NZX * 2);
    unsigned short* xbc   = (unsigned short*)alloc((size_t)2 * NROWS * 1280 * 2);
    float* Gbuf           = (float*)alloc((size_t)2 * 128 * 4096 * 4);
    float* dtb            = (float*)alloc((size_t)2 * 2048 * 64 * 4);
    float* csb            = (float*)alloc((size_t)2 * 2048 * 64 * 4);
    unsigned short* ybh   = (unsigned short*)alloc((size_t)NROWS * 1024 * 2);
    unsigned short* ybv   = (unsigned short*)alloc((size_t)NROWS * 1024 * 2);

    prep_kernel<<<PB4, 256, 0, stream>>>(x, fcw, iw0, iw1, ow0, ow1, db0, db1,
                                         al0, al1, xbf, wf, wbA, wbOT0, wbOT1,
                                         dtb, csb);
    gemm_big<<<dim3(296, 1, 2), 512, 0, stream>>>(xbf, wbA, zx, wf,
                                                  wbOT0, wbOT1, wcomb,
                                                  cw0, cw1, cb0, cb1, xbc);
    gmat_kernel<<<dim3(128, 2), 256, 0, stream>>>(xbc, Gbuf);
    scan_kernel<<<dim3(2048, 2), 256, 0, stream>>>(xbc, Gbuf, dtb, csb,
                                                   Dv0, Dv1, ybh, ybv);
    gate_norm<<<dim3(NROWS, 2), 128, 0, stream>>>(zx, ybh, ybv, nw0, nw1);
    gemm_final2048<<<dim3(64, 8), 256, 0, stream>>>(ybv, ybh, wcomb, fcb, (float*)d_out);
}